// Round 1
// baseline (892.440 us; speedup 1.0000x reference)
//
#include <hip/hip_runtime.h>
#include <math.h>

#define BB 4
#define NN 4096
#define CC 1024
#define HH 16
#define HD 64
#define LM 64
#define SEG 64
#define BHN (BB*HH)          // 64
#define MATP 65              // padded row stride for 64x64 LDS tiles
#define MATE (64*MATP)       // 4160 floats

// ---------------- Kernel A: landmark means ----------------
// grid (16, BH), block 256. Each block: 4 landmarks (l = 4*bx + tid>>6), d = tid&63.
__global__ __launch_bounds__(256) void lm_kernel(
    const float* __restrict__ Q, const float* __restrict__ K,
    float* __restrict__ qlm, float* __restrict__ klm) {
  int bh = blockIdx.y; int b = bh >> 4; int h = bh & 15;
  int tid = threadIdx.x;
  int l = blockIdx.x * 4 + (tid >> 6);
  int d = tid & 63;
  const float* qbase = Q + ((size_t)b*NN + (size_t)l*SEG)*CC + h*HD + d;
  const float* kbase = K + ((size_t)b*NN + (size_t)l*SEG)*CC + h*HD + d;
  float sq = 0.f, sk = 0.f;
#pragma unroll 8
  for (int s = 0; s < SEG; ++s) {
    sq += qbase[(size_t)s*CC];
    sk += kbase[(size_t)s*CC];
  }
  qlm[(size_t)bh*4096 + l*64 + d] = sq * (1.0f/(64.0f*8.0f));  // mean, then /sqrt(hd)
  klm[(size_t)bh*4096 + l*64 + d] = sk * (1.0f/64.0f);
}

// ---------------- Kernel B: T-partials = softmax(q_lm K^T) V ----------------
// grid (16, BH), block 256. Each block: 256 n values (4 sub-chunks of 64).
// LDS: qs [64][65], KE [64][65] (K tile, reused for E), Vc [64][65]  (~49.9 KB static)
__global__ __launch_bounds__(256) void k3v_kernel(
    const float* __restrict__ K, const float* __restrict__ V,
    const float* __restrict__ qlm,
    float* __restrict__ S3, float* __restrict__ ACC3) {
  __shared__ float qs[MATE];
  __shared__ float KE[MATE];
  __shared__ float Vc[MATE];
  int bh = blockIdx.y; int b = bh >> 4; int h = bh & 15;
  int tile = blockIdx.x; int tid = threadIdx.x;

  for (int e = tid; e < 4096; e += 256)
    qs[(e>>6)*MATP + (e&63)] = qlm[(size_t)bh*4096 + e];

  int l = tid >> 2, qtr = tid & 3;
  float acc[16];
#pragma unroll
  for (int j = 0; j < 16; ++j) acc[j] = 0.f;
  float spart = 0.f;

  for (int sub = 0; sub < 4; ++sub) {
    int n0 = tile*256 + sub*64;
    __syncthreads();   // protect KE/Vc from previous iteration's readers
    for (int e = tid; e < 4096; e += 256) {
      int r = e>>6, d = e&63;
      size_t g = ((size_t)b*NN + n0 + r)*CC + h*HD + d;
      KE[r*MATP + d] = K[g];
      Vc[r*MATP + d] = V[g];
    }
    __syncthreads();
    // logits for (l, n=qtr*16+j) into registers (KE still holds K tile)
    float z[16];
#pragma unroll
    for (int j = 0; j < 16; ++j) {
      int n = qtr*16 + j;
      float s = 0.f;
#pragma unroll
      for (int k = 0; k < 64; ++k) s += qs[l*MATP+k] * KE[n*MATP+k];
      z[j] = s;
    }
    __syncthreads();
    // overwrite KE with E = exp(z)
#pragma unroll
    for (int j = 0; j < 16; ++j) KE[l*MATP + qtr*16 + j] = expf(z[j]);
    __syncthreads();
    // partial row sums (each quarter covers distinct n range)
#pragma unroll
    for (int j = 0; j < 16; ++j) spart += KE[l*MATP + qtr*16 + j];
    // acc[l][d] over this chunk, d = qtr*16+j
#pragma unroll
    for (int j = 0; j < 16; ++j) {
      int d = qtr*16 + j;
      float s = 0.f;
#pragma unroll
      for (int n = 0; n < 64; ++n) s += KE[l*MATP+n] * Vc[n*MATP+d];
      acc[j] += s;
    }
  }
  atomicAdd(&S3[bh*64 + l], spart);
#pragma unroll
  for (int j = 0; j < 16; ++j)
    atomicAdd(&ACC3[(size_t)bh*4096 + l*64 + qtr*16 + j], acc[j]);
}

// ---------------- Kernel C: kernel_2 softmax + Newton-Schulz inverse + W ----------------
// grid (BH), block 1024, dynamic LDS: K2,P1..P4 [64][65] + srow[64]
__device__ __forceinline__ void mm64(float* __restrict__ O, const float* __restrict__ X,
                                     const float* __restrict__ Y, int tid, float alpha) {
  for (int e = tid; e < 4096; e += 1024) {
    int i = e>>6, j = e&63;
    float s = 0.f;
#pragma unroll
    for (int k = 0; k < 64; ++k) s += X[i*MATP+k]*Y[k*MATP+j];
    O[i*MATP+j] = alpha*s;
  }
  __syncthreads();
}
__device__ __forceinline__ void diagsub(float* __restrict__ O, const float* __restrict__ X,
                                        float c, int tid) {
  for (int e = tid; e < 4096; e += 1024) {
    int i = e>>6, j = e&63;
    O[i*MATP+j] = (i==j ? c : 0.f) - X[i*MATP+j];
  }
  __syncthreads();
}

__global__ __launch_bounds__(1024) void inv_kernel(
    const float* __restrict__ qlm, const float* __restrict__ klm,
    const float* __restrict__ S3, const float* __restrict__ ACC3,
    float* __restrict__ W) {
  extern __shared__ float smem[];
  float* K2 = smem;
  float* P1 = smem + 1*MATE;
  float* P2 = smem + 2*MATE;
  float* P3 = smem + 3*MATE;
  float* P4 = smem + 4*MATE;
  float* srow = smem + 5*MATE;   // 64
  int bh = blockIdx.x; int tid = threadIdx.x;

  // stage qlm -> P1, klm -> P2
  for (int e = tid; e < 4096; e += 1024) {
    P1[(e>>6)*MATP+(e&63)] = qlm[(size_t)bh*4096+e];
    P2[(e>>6)*MATP+(e&63)] = klm[(size_t)bh*4096+e];
  }
  __syncthreads();
  // kernel_2 logits + exp
  for (int e = tid; e < 4096; e += 1024) {
    int i = e>>6, j = e&63;
    float z = 0.f;
#pragma unroll
    for (int k = 0; k < 64; ++k) z += P1[i*MATP+k]*P2[j*MATP+k];
    K2[i*MATP+j] = expf(z);
  }
  __syncthreads();
  if (tid < 64) {
    float s = 0.f;
    for (int j = 0; j < 64; ++j) s += K2[tid*MATP+j];
    srow[tid] = 1.0f/s;
  }
  __syncthreads();
  for (int e = tid; e < 4096; e += 1024)
    K2[(e>>6)*MATP+(e&63)] *= srow[e>>6];
  __syncthreads();
  // column sums -> denom = max_j
  if (tid < 64) {
    float c = 0.f;
    for (int i = 0; i < 64; ++i) c += K2[i*MATP+tid];
    for (int off = 32; off > 0; off >>= 1)
      c = fmaxf(c, __shfl_xor(c, off, 64));
    if (tid == 0) srow[0] = 1.0f/c;
  }
  __syncthreads();
  float invden = srow[0];
  __syncthreads();
  // Vm init = K2^T / denom -> P1
  for (int e = tid; e < 4096; e += 1024) {
    int i = e>>6, j = e&63;
    P1[i*MATP+j] = K2[j*MATP+i] * invden;
  }
  __syncthreads();

  float *Vm = P1, *fA = P2, *fB = P3, *fC = P4;
  for (int it = 0; it < 6; ++it) {
    mm64(fB, K2, Vm, tid, 1.0f);      // KV
    diagsub(fC, fB, 7.0f, tid);       // 7I - KV
    mm64(fA, fB, fC, tid, 1.0f);      // KV(7I-KV)
    diagsub(fC, fA, 15.0f, tid);      // 15I - ...
    mm64(fA, fB, fC, tid, 1.0f);      // KV(15I-...)
    diagsub(fC, fA, 13.0f, tid);      // 13I - ...
    mm64(fB, Vm, fC, tid, 0.25f);     // 0.25 Vm (...) -> fB (KV dead)
    float* t = Vm; Vm = fB; fB = t;
  }
  // T = ACC3 / S3 -> fC ; W = Vm @ T
  for (int e = tid; e < 4096; e += 1024) {
    int k2 = e>>6, j = e&63;
    fC[k2*MATP+j] = ACC3[(size_t)bh*4096+e] / S3[bh*64+k2];
  }
  __syncthreads();
  for (int e = tid; e < 4096; e += 1024) {
    int i = e>>6, j = e&63;
    float s = 0.f;
#pragma unroll
    for (int k = 0; k < 64; ++k) s += Vm[i*MATP+k]*fC[k*MATP+j];
    W[(size_t)bh*4096+e] = s;
  }
}

// ---------------- Kernel D: out = softmax(q k_lm^T) @ W ----------------
// grid (64, BH), block 256. LDS: QE [64][65] (Q tile, reused for E and O), Kl, Ws + srow
__global__ __launch_bounds__(256) void out_kernel(
    const float* __restrict__ Q, const float* __restrict__ klm,
    const float* __restrict__ W, float* __restrict__ Out) {
  __shared__ float QE[MATE];
  __shared__ float Kl[MATE];
  __shared__ float Ws[MATE];
  __shared__ float srow[64];
  int bh = blockIdx.y, b = bh>>4, h = bh&15;
  int n0 = blockIdx.x * 64;
  int tid = threadIdx.x;
  for (int e = tid; e < 4096; e += 256) {
    int r = e>>6, d = e&63;
    QE[r*MATP+d] = Q[((size_t)b*NN + n0 + r)*CC + h*HD + d] * 0.125f;
    Kl[r*MATP+d] = klm[(size_t)bh*4096+e];
    Ws[r*MATP+d] = W[(size_t)bh*4096+e];
  }
  __syncthreads();
  int r = tid>>2, qtr = tid&3;
  float z[16];
#pragma unroll
  for (int j = 0; j < 16; ++j) {
    int l = qtr*16+j;
    float s = 0.f;
#pragma unroll
    for (int k = 0; k < 64; ++k) s += QE[r*MATP+k]*Kl[l*MATP+k];
    z[j] = s;
  }
  __syncthreads();
#pragma unroll
  for (int j = 0; j < 16; ++j) QE[r*MATP + qtr*16 + j] = expf(z[j]);
  __syncthreads();
  if (tid < 64) {
    float s = 0.f;
    for (int l2 = 0; l2 < 64; ++l2) s += QE[tid*MATP+l2];
    srow[tid] = 1.0f/s;
  }
  __syncthreads();
  float rs = srow[r];
  float o[16];
#pragma unroll
  for (int j = 0; j < 16; ++j) {
    int d = qtr*16+j;
    float s = 0.f;
#pragma unroll
    for (int l2 = 0; l2 < 64; ++l2) s += QE[r*MATP+l2]*Ws[l2*MATP+d];
    o[j] = s * rs;
  }
  __syncthreads();
#pragma unroll
  for (int j = 0; j < 16; ++j) QE[r*MATP + qtr*16 + j] = o[j];
  __syncthreads();
  for (int e = tid; e < 4096; e += 256) {
    int rr = e>>6, d = e&63;
    Out[((size_t)b*NN + n0 + rr)*CC + h*HD + d] = QE[rr*MATP+d];
  }
}

// ---------------- host ----------------
extern "C" void kernel_launch(void* const* d_in, const int* in_sizes, int n_in,
                              void* d_out, int out_size, void* d_ws, size_t ws_size,
                              hipStream_t stream) {
  const float* Q = (const float*)d_in[0];
  const float* K = (const float*)d_in[1];
  const float* V = (const float*)d_in[2];
  float* out = (float*)d_out;
  float* ws  = (float*)d_ws;

  float* qlm  = ws;               // 262144
  float* klm  = ws + 262144;      // 262144
  float* S3   = ws + 524288;      // 4096
  float* ACC3 = ws + 528384;      // 262144
  float* Wm   = ws + 790528;      // 262144

  size_t shC = (size_t)(5*MATE + 64)*sizeof(float);
  hipFuncSetAttribute((const void*)inv_kernel,
                      hipFuncAttributeMaxDynamicSharedMemorySize, (int)shC);

  // zero S3 + ACC3 (contiguous)
  hipMemsetAsync(S3, 0, (4096 + 262144)*sizeof(float), stream);

  lm_kernel <<<dim3(16, BHN), 256, 0, stream>>>(Q, K, qlm, klm);
  k3v_kernel<<<dim3(16, BHN), 256, 0, stream>>>(K, V, qlm, S3, ACC3);
  inv_kernel<<<dim3(BHN),    1024, shC, stream>>>(qlm, klm, S3, ACC3, Wm);
  out_kernel<<<dim3(64, BHN), 256, 0, stream>>>(Q, klm, Wm, out);
}

// Round 2
// 306.144 us; speedup vs baseline: 2.9151x; 2.9151x over previous
//
#include <hip/hip_runtime.h>
#include <math.h>

#define BB 4
#define NN 4096
#define CC 1024
#define HH 16
#define HD 64
#define LM 64
#define SEG 64
#define BHN (BB*HH)          // 64
#define MATP 68              // row stride (floats): 16B-aligned rows, lane-stride 68%32=4 -> conflict-free b128
#define MATE (64*MATP)       // 4352 floats per 64x64 tile

__device__ __forceinline__ float shfl_sum16(float v) {
  v += __shfl_xor(v, 1, 16);
  v += __shfl_xor(v, 2, 16);
  v += __shfl_xor(v, 4, 16);
  v += __shfl_xor(v, 8, 16);
  return v;
}

// ---------------- Kernel A: landmark means ----------------
__global__ __launch_bounds__(256) void lm_kernel(
    const float* __restrict__ Q, const float* __restrict__ K,
    float* __restrict__ qlm, float* __restrict__ klm) {
  int bh = blockIdx.y; int b = bh >> 4; int h = bh & 15;
  int tid = threadIdx.x;
  int l = blockIdx.x * 4 + (tid >> 6);
  int d = tid & 63;
  const float* qbase = Q + ((size_t)b*NN + (size_t)l*SEG)*CC + h*HD + d;
  const float* kbase = K + ((size_t)b*NN + (size_t)l*SEG)*CC + h*HD + d;
  float sq = 0.f, sk = 0.f;
#pragma unroll 8
  for (int s = 0; s < SEG; ++s) {
    sq += qbase[(size_t)s*CC];
    sk += kbase[(size_t)s*CC];
  }
  qlm[(size_t)bh*4096 + l*64 + d] = sq * (1.0f/(64.0f*8.0f));  // mean then /sqrt(hd)
  klm[(size_t)bh*4096 + l*64 + d] = sk * (1.0f/64.0f);
}

// ---------------- Kernel B: partials of kernel_3 @ V (pre-normalization) ----------------
// grid (16, BH), block 256. Tile ownership: rows l = ti+16*il, cols = tj+16*jn.
__global__ __launch_bounds__(256) void k3v_kernel(
    const float* __restrict__ K, const float* __restrict__ V,
    const float* __restrict__ qlm,
    float* __restrict__ S3, float* __restrict__ ACC3) {
  __shared__ float qs[MATE];
  __shared__ float KE[MATE];
  __shared__ float Vc[MATE];
  const int bh = blockIdx.y, b = bh >> 4, h = bh & 15;
  const int tile = blockIdx.x, tid = threadIdx.x;
  const int ti = tid >> 4, tj = tid & 15;

#pragma unroll
  for (int q = 0; q < 4; ++q) {
    int f = tid + 256*q;
    int r = f >> 4, c4 = (f & 15) << 2;
    *(float4*)&qs[r*MATP + c4] = *(const float4*)&qlm[(size_t)bh*4096 + f*4];
  }

  float acc[4][4];
#pragma unroll
  for (int i = 0; i < 4; ++i)
#pragma unroll
    for (int j = 0; j < 4; ++j) acc[i][j] = 0.f;
  float srow[4] = {0.f, 0.f, 0.f, 0.f};

  for (int sub = 0; sub < 4; ++sub) {
    const int n0 = tile*256 + sub*64;
    __syncthreads();
#pragma unroll
    for (int q = 0; q < 4; ++q) {
      int f = tid + 256*q;
      int r = f >> 4, c4 = (f & 15) << 2;
      size_t g = ((size_t)b*NN + n0 + r)*CC + h*HD + c4;
      *(float4*)&KE[r*MATP + c4] = *(const float4*)&K[g];
      *(float4*)&Vc[r*MATP + c4] = *(const float4*)&V[g];
    }
    __syncthreads();
    // GEMM1: z[il][jn] = sum_k qs[ti+16il][k] * K[tj+16jn][k]
    float z[4][4];
#pragma unroll
    for (int i = 0; i < 4; ++i)
#pragma unroll
      for (int j = 0; j < 4; ++j) z[i][j] = 0.f;
#pragma unroll 4
    for (int kk = 0; kk < 16; ++kk) {
      float4 a[4], bb[4];
#pragma unroll
      for (int il = 0; il < 4; ++il) a[il] = *(const float4*)&qs[(ti+16*il)*MATP + 4*kk];
#pragma unroll
      for (int jn = 0; jn < 4; ++jn) bb[jn] = *(const float4*)&KE[(tj+16*jn)*MATP + 4*kk];
#pragma unroll
      for (int il = 0; il < 4; ++il)
#pragma unroll
        for (int jn = 0; jn < 4; ++jn)
          z[il][jn] += a[il].x*bb[jn].x + a[il].y*bb[jn].y + a[il].z*bb[jn].z + a[il].w*bb[jn].w;
    }
    __syncthreads();   // done reading K tile
    // exp + row-sum partial + write E into KE
#pragma unroll
    for (int il = 0; il < 4; ++il) {
      float e0 = expf(z[il][0]), e1 = expf(z[il][1]), e2 = expf(z[il][2]), e3 = expf(z[il][3]);
      float v = shfl_sum16(e0 + e1 + e2 + e3);
      srow[il] += v;
      int rb = (ti + 16*il)*MATP + tj;
      KE[rb]      = e0;
      KE[rb + 16] = e1;
      KE[rb + 32] = e2;
      KE[rb + 48] = e3;
    }
    __syncthreads();
    // GEMM2: acc[il][jn] += sum_n E[ti+16il][n] * V[n][tj+16jn]
#pragma unroll 4
    for (int kk = 0; kk < 16; ++kk) {
      float4 a[4];
#pragma unroll
      for (int il = 0; il < 4; ++il) a[il] = *(const float4*)&KE[(ti+16*il)*MATP + 4*kk];
      float bb[4][4];
#pragma unroll
      for (int kq = 0; kq < 4; ++kq)
#pragma unroll
        for (int jn = 0; jn < 4; ++jn)
          bb[kq][jn] = Vc[(4*kk + kq)*MATP + tj + 16*jn];
#pragma unroll
      for (int il = 0; il < 4; ++il)
#pragma unroll
        for (int jn = 0; jn < 4; ++jn)
          acc[il][jn] += a[il].x*bb[0][jn] + a[il].y*bb[1][jn] + a[il].z*bb[2][jn] + a[il].w*bb[3][jn];
    }
  }
  if (tj == 0) {
#pragma unroll
    for (int il = 0; il < 4; ++il)
      atomicAdd(&S3[bh*64 + ti + 16*il], srow[il]);
  }
#pragma unroll
  for (int il = 0; il < 4; ++il)
#pragma unroll
    for (int jn = 0; jn < 4; ++jn)
      atomicAdd(&ACC3[(size_t)bh*4096 + (ti+16*il)*64 + tj + 16*jn], acc[il][jn]);
}

// ---------------- Kernel C: kernel_2 softmax + Newton-Schulz inverse + W = V^-1 T ----------------
// 256 threads, dynamic LDS: K2 + 4 work buffers + csum[64] + sden
__device__ __forceinline__ void mm64t(float* __restrict__ O,
    const float* __restrict__ A, const float* __restrict__ B,
    float diagc, float scale, bool fuse, int ti, int tj) {
  float acc[4][4];
#pragma unroll
  for (int i = 0; i < 4; ++i)
#pragma unroll
    for (int j = 0; j < 4; ++j) acc[i][j] = 0.f;
#pragma unroll 4
  for (int kk = 0; kk < 16; ++kk) {
    float4 a[4];
#pragma unroll
    for (int il = 0; il < 4; ++il) a[il] = *(const float4*)&A[(ti+16*il)*MATP + 4*kk];
    float bb[4][4];
#pragma unroll
    for (int kq = 0; kq < 4; ++kq)
#pragma unroll
      for (int jn = 0; jn < 4; ++jn) {
        float y = B[(4*kk + kq)*MATP + tj + 16*jn];
        if (fuse) {
          y = -y;
          if (4*kk + kq == tj + 16*jn) y += diagc;
        }
        bb[kq][jn] = y;
      }
#pragma unroll
    for (int il = 0; il < 4; ++il)
#pragma unroll
      for (int jn = 0; jn < 4; ++jn)
        acc[il][jn] += a[il].x*bb[0][jn] + a[il].y*bb[1][jn] + a[il].z*bb[2][jn] + a[il].w*bb[3][jn];
  }
#pragma unroll
  for (int il = 0; il < 4; ++il)
#pragma unroll
    for (int jn = 0; jn < 4; ++jn)
      O[(ti+16*il)*MATP + tj + 16*jn] = scale * acc[il][jn];
  __syncthreads();
}

__global__ __launch_bounds__(256) void inv_kernel(
    const float* __restrict__ qlm, const float* __restrict__ klm,
    const float* __restrict__ S3, const float* __restrict__ ACC3,
    float* __restrict__ W) {
  extern __shared__ float smem[];
  float* K2 = smem;
  float* B1 = smem + 1*MATE;
  float* B2 = smem + 2*MATE;
  float* B3 = smem + 3*MATE;
  float* B4 = smem + 4*MATE;
  float* csum = smem + 5*MATE;   // 64
  float* sden = csum + 64;       // 1
  const int bh = blockIdx.x, tid = threadIdx.x;
  const int ti = tid >> 4, tj = tid & 15;

#pragma unroll
  for (int q = 0; q < 4; ++q) {
    int f = tid + 256*q;
    int r = f >> 4, c4 = (f & 15) << 2;
    *(float4*)&B1[r*MATP + c4] = *(const float4*)&qlm[(size_t)bh*4096 + f*4];
    *(float4*)&B2[r*MATP + c4] = *(const float4*)&klm[(size_t)bh*4096 + f*4];
  }
  if (tid < 64) csum[tid] = 0.f;
  __syncthreads();

  // kernel_2: z = qlm @ klm^T, softmax rows, write K2; column-sum partials
  float z[4][4];
#pragma unroll
  for (int i = 0; i < 4; ++i)
#pragma unroll
    for (int j = 0; j < 4; ++j) z[i][j] = 0.f;
#pragma unroll 4
  for (int kk = 0; kk < 16; ++kk) {
    float4 a[4], bb[4];
#pragma unroll
    for (int il = 0; il < 4; ++il) a[il] = *(const float4*)&B1[(ti+16*il)*MATP + 4*kk];
#pragma unroll
    for (int jn = 0; jn < 4; ++jn) bb[jn] = *(const float4*)&B2[(tj+16*jn)*MATP + 4*kk];
#pragma unroll
    for (int il = 0; il < 4; ++il)
#pragma unroll
      for (int jn = 0; jn < 4; ++jn)
        z[il][jn] += a[il].x*bb[jn].x + a[il].y*bb[jn].y + a[il].z*bb[jn].z + a[il].w*bb[jn].w;
  }
  __syncthreads();
  float colp[4] = {0.f, 0.f, 0.f, 0.f};
#pragma unroll
  for (int il = 0; il < 4; ++il) {
    float e[4]; float v = 0.f;
#pragma unroll
    for (int jn = 0; jn < 4; ++jn) { e[jn] = expf(z[il][jn]); v += e[jn]; }
    v = shfl_sum16(v);
    float ri = 1.0f / v;
#pragma unroll
    for (int jn = 0; jn < 4; ++jn) {
      float p = e[jn] * ri;
      K2[(ti+16*il)*MATP + tj + 16*jn] = p;
      colp[jn] += p;
    }
  }
#pragma unroll
  for (int jn = 0; jn < 4; ++jn) atomicAdd(&csum[tj + 16*jn], colp[jn]);
  __syncthreads();
  if (tid < 64) {
    float c = csum[tid];
#pragma unroll
    for (int m = 1; m < 64; m <<= 1) c = fmaxf(c, __shfl_xor(c, m, 64));
    if (tid == 0) sden[0] = 1.0f / c;
  }
  __syncthreads();
  const float invden = sden[0];
  // Vm init = K2^T * invden -> B1
#pragma unroll
  for (int il = 0; il < 4; ++il)
#pragma unroll
    for (int jn = 0; jn < 4; ++jn)
      B1[(ti+16*il)*MATP + tj + 16*jn] = K2[(tj+16*jn)*MATP + ti + 16*il] * invden;
  __syncthreads();

  float *Vm = B1, *t1 = B2, *sp = B3, *sq = B4;
  for (int it = 0; it < 6; ++it) {
    mm64t(t1, K2, Vm, 0.f, 1.0f, false, ti, tj);   // KV
    mm64t(sp, t1, t1, 7.f, 1.0f, true, ti, tj);    // KV(7I-KV)
    mm64t(sq, t1, sp, 15.f, 1.0f, true, ti, tj);   // KV(15I-...)
    mm64t(t1, Vm, sq, 13.f, 0.25f, true, ti, tj);  // 0.25 Vm (13I-...)
    float* tmp = Vm; Vm = t1; t1 = tmp;
  }

  // T = ACC3 / S3 -> sp
#pragma unroll
  for (int q = 0; q < 4; ++q) {
    int f = tid + 256*q;
    int r = f >> 4, c4 = (f & 15) << 2;
    float4 tv = *(const float4*)&ACC3[(size_t)bh*4096 + f*4];
    float ri = 1.0f / S3[bh*64 + r];
    tv.x *= ri; tv.y *= ri; tv.z *= ri; tv.w *= ri;
    *(float4*)&sp[r*MATP + c4] = tv;
  }
  __syncthreads();
  // W = Vm @ T  (write global)
  float acc[4][4];
#pragma unroll
  for (int i = 0; i < 4; ++i)
#pragma unroll
    for (int j = 0; j < 4; ++j) acc[i][j] = 0.f;
#pragma unroll 4
  for (int kk = 0; kk < 16; ++kk) {
    float4 a[4];
#pragma unroll
    for (int il = 0; il < 4; ++il) a[il] = *(const float4*)&Vm[(ti+16*il)*MATP + 4*kk];
    float bb[4][4];
#pragma unroll
    for (int kq = 0; kq < 4; ++kq)
#pragma unroll
      for (int jn = 0; jn < 4; ++jn)
        bb[kq][jn] = sp[(4*kk + kq)*MATP + tj + 16*jn];
#pragma unroll
    for (int il = 0; il < 4; ++il)
#pragma unroll
      for (int jn = 0; jn < 4; ++jn)
        acc[il][jn] += a[il].x*bb[0][jn] + a[il].y*bb[1][jn] + a[il].z*bb[2][jn] + a[il].w*bb[3][jn];
  }
#pragma unroll
  for (int il = 0; il < 4; ++il)
#pragma unroll
    for (int jn = 0; jn < 4; ++jn)
      W[(size_t)bh*4096 + (ti+16*il)*64 + tj + 16*jn] = acc[il][jn];
}

// ---------------- Kernel D: out = softmax(q k_lm^T) @ W ----------------
__global__ __launch_bounds__(256) void out_kernel(
    const float* __restrict__ Q, const float* __restrict__ klm,
    const float* __restrict__ W, float* __restrict__ Out) {
  __shared__ float QE[MATE];
  __shared__ float Kl[MATE];
  __shared__ float Ws[MATE];
  const int bh = blockIdx.y, b = bh >> 4, h = bh & 15;
  const int n0 = blockIdx.x * 64;
  const int tid = threadIdx.x, ti = tid >> 4, tj = tid & 15;

#pragma unroll
  for (int q = 0; q < 4; ++q) {
    int f = tid + 256*q;
    int r = f >> 4, c4 = (f & 15) << 2;
    float4 qv = *(const float4*)&Q[((size_t)b*NN + n0 + r)*CC + h*HD + c4];
    qv.x *= 0.125f; qv.y *= 0.125f; qv.z *= 0.125f; qv.w *= 0.125f;
    *(float4*)&QE[r*MATP + c4] = qv;
    *(float4*)&Kl[r*MATP + c4] = *(const float4*)&klm[(size_t)bh*4096 + f*4];
    *(float4*)&Ws[r*MATP + c4] = *(const float4*)&W[(size_t)bh*4096 + f*4];
  }
  __syncthreads();
  // GEMM1: z = QE rows . Kl rows
  float z[4][4];
#pragma unroll
  for (int i = 0; i < 4; ++i)
#pragma unroll
    for (int j = 0; j < 4; ++j) z[i][j] = 0.f;
#pragma unroll 4
  for (int kk = 0; kk < 16; ++kk) {
    float4 a[4], bb[4];
#pragma unroll
    for (int il = 0; il < 4; ++il) a[il] = *(const float4*)&QE[(ti+16*il)*MATP + 4*kk];
#pragma unroll
    for (int jn = 0; jn < 4; ++jn) bb[jn] = *(const float4*)&Kl[(tj+16*jn)*MATP + 4*kk];
#pragma unroll
    for (int il = 0; il < 4; ++il)
#pragma unroll
      for (int jn = 0; jn < 4; ++jn)
        z[il][jn] += a[il].x*bb[jn].x + a[il].y*bb[jn].y + a[il].z*bb[jn].z + a[il].w*bb[jn].w;
  }
  __syncthreads();
  // P = exp(z)/rowsum -> QE
#pragma unroll
  for (int il = 0; il < 4; ++il) {
    float e0 = expf(z[il][0]), e1 = expf(z[il][1]), e2 = expf(z[il][2]), e3 = expf(z[il][3]);
    float v = shfl_sum16(e0 + e1 + e2 + e3);
    float ri = 1.0f / v;
    int rb = (ti + 16*il)*MATP + tj;
    QE[rb]      = e0 * ri;
    QE[rb + 16] = e1 * ri;
    QE[rb + 32] = e2 * ri;
    QE[rb + 48] = e3 * ri;
  }
  __syncthreads();
  // GEMM2: o = P @ Ws
  float o[4][4];
#pragma unroll
  for (int i = 0; i < 4; ++i)
#pragma unroll
    for (int j = 0; j < 4; ++j) o[i][j] = 0.f;
#pragma unroll 4
  for (int kk = 0; kk < 16; ++kk) {
    float4 a[4];
#pragma unroll
    for (int il = 0; il < 4; ++il) a[il] = *(const float4*)&QE[(ti+16*il)*MATP + 4*kk];
    float bb[4][4];
#pragma unroll
    for (int kq = 0; kq < 4; ++kq)
#pragma unroll
      for (int jn = 0; jn < 4; ++jn)
        bb[kq][jn] = Ws[(4*kk + kq)*MATP + tj + 16*jn];
#pragma unroll
    for (int il = 0; il < 4; ++il)
#pragma unroll
      for (int jn = 0; jn < 4; ++jn)
        o[il][jn] += a[il].x*bb[0][jn] + a[il].y*bb[1][jn] + a[il].z*bb[2][jn] + a[il].w*bb[3][jn];
  }
  // stage O tile into Kl for coalesced float4 writeback
#pragma unroll
  for (int il = 0; il < 4; ++il)
#pragma unroll
    for (int jn = 0; jn < 4; ++jn)
      Kl[(ti+16*il)*MATP + tj + 16*jn] = o[il][jn];
  __syncthreads();
#pragma unroll
  for (int q = 0; q < 4; ++q) {
    int f = tid + 256*q;
    int r = f >> 4, c4 = (f & 15) << 2;
    *(float4*)&Out[((size_t)b*NN + n0 + r)*CC + h*HD + c4] = *(float4*)&Kl[r*MATP + c4];
  }
}

// ---------------- host ----------------
extern "C" void kernel_launch(void* const* d_in, const int* in_sizes, int n_in,
                              void* d_out, int out_size, void* d_ws, size_t ws_size,
                              hipStream_t stream) {
  const float* Q = (const float*)d_in[0];
  const float* K = (const float*)d_in[1];
  const float* V = (const float*)d_in[2];
  float* out = (float*)d_out;
  float* ws  = (float*)d_ws;

  float* qlm  = ws;               // 262144
  float* klm  = ws + 262144;      // 262144
  float* S3   = ws + 524288;      // 4096
  float* ACC3 = ws + 528384;      // 262144
  float* Wm   = ws + 790528;      // 262144

  size_t shC = (size_t)(5*MATE + 68)*sizeof(float);
  hipFuncSetAttribute((const void*)inv_kernel,
                      hipFuncAttributeMaxDynamicSharedMemorySize, (int)shC);

  // zero S3 + ACC3 (contiguous)
  hipMemsetAsync(S3, 0, (4096 + 262144)*sizeof(float), stream);

  lm_kernel <<<dim3(16, BHN), 256, 0, stream>>>(Q, K, qlm, klm);
  k3v_kernel<<<dim3(16, BHN), 256, 0, stream>>>(K, V, qlm, S3, ACC3);
  inv_kernel<<<dim3(BHN),     256, shC, stream>>>(qlm, klm, S3, ACC3, Wm);
  out_kernel<<<dim3(64, BHN), 256, 0, stream>>>(Q, klm, Wm, out);
}

// Round 3
// 236.186 us; speedup vs baseline: 3.7786x; 1.2962x over previous
//
#include <hip/hip_runtime.h>
#include <math.h>

#define BB 4
#define NN 4096
#define CC 1024
#define HH 16
#define HD 64
#define LM 64
#define SEG 64
#define BHN (BB*HH)          // 64
#define MATP 68              // fp32 row stride: 16B-aligned rows, lane-stride 68%32=4
#define MATE (64*MATP)       // 4352 floats per 64x64 tile

typedef __attribute__((ext_vector_type(8))) short bf16x8;
typedef __attribute__((ext_vector_type(4))) float f32x4;

__device__ __forceinline__ float shfl_sum16(float v) {
  v += __shfl_xor(v, 1, 16);
  v += __shfl_xor(v, 2, 16);
  v += __shfl_xor(v, 4, 16);
  v += __shfl_xor(v, 8, 16);
  return v;
}

// split fp32 -> bf16 hi (chop) + bf16 lo (chop of residual); rel err ~2^-16
__device__ __forceinline__ void split8(const float* f, bf16x8& hi, bf16x8& lo) {
#pragma unroll
  for (int i = 0; i < 8; ++i) {
    unsigned u = __builtin_bit_cast(unsigned, f[i]);
    float hf = __builtin_bit_cast(float, u & 0xFFFF0000u);
    hi[i] = (short)(u >> 16);
    float l = f[i] - hf;
    unsigned ul = __builtin_bit_cast(unsigned, l);
    lo[i] = (short)(ul >> 16);
  }
}

// ---------------- Kernel A: landmark means ----------------
__global__ __launch_bounds__(256) void lm_kernel(
    const float* __restrict__ Q, const float* __restrict__ K,
    float* __restrict__ qlm, float* __restrict__ klm) {
  int bh = blockIdx.y; int b = bh >> 4; int h = bh & 15;
  int tid = threadIdx.x;
  int l = blockIdx.x * 4 + (tid >> 6);
  int d = tid & 63;
  const float* qbase = Q + ((size_t)b*NN + (size_t)l*SEG)*CC + h*HD + d;
  const float* kbase = K + ((size_t)b*NN + (size_t)l*SEG)*CC + h*HD + d;
  float sq = 0.f, sk = 0.f;
#pragma unroll 8
  for (int s = 0; s < SEG; ++s) {
    sq += qbase[(size_t)s*CC];
    sk += kbase[(size_t)s*CC];
  }
  qlm[(size_t)bh*4096 + l*64 + d] = sq * (1.0f/(64.0f*8.0f));  // mean then /sqrt(hd)
  klm[(size_t)bh*4096 + l*64 + d] = sk * (1.0f/64.0f);
}

// ---------------- Kernel B: partials of kernel_3 @ V (pre-normalization) ----------------
__global__ __launch_bounds__(256) void k3v_kernel(
    const float* __restrict__ K, const float* __restrict__ V,
    const float* __restrict__ qlm,
    float* __restrict__ S3, float* __restrict__ ACC3) {
  __shared__ float qs[MATE];
  __shared__ float KE[MATE];
  __shared__ float Vc[MATE];
  const int bh = blockIdx.y, b = bh >> 4, h = bh & 15;
  const int tile = blockIdx.x, tid = threadIdx.x;
  const int ti = tid >> 4, tj = tid & 15;

#pragma unroll
  for (int q = 0; q < 4; ++q) {
    int f = tid + 256*q;
    int r = f >> 4, c4 = (f & 15) << 2;
    *(float4*)&qs[r*MATP + c4] = *(const float4*)&qlm[(size_t)bh*4096 + f*4];
  }

  float acc[4][4];
#pragma unroll
  for (int i = 0; i < 4; ++i)
#pragma unroll
    for (int j = 0; j < 4; ++j) acc[i][j] = 0.f;
  float srow[4] = {0.f, 0.f, 0.f, 0.f};

  for (int sub = 0; sub < 4; ++sub) {
    const int n0 = tile*256 + sub*64;
    __syncthreads();
#pragma unroll
    for (int q = 0; q < 4; ++q) {
      int f = tid + 256*q;
      int r = f >> 4, c4 = (f & 15) << 2;
      size_t g = ((size_t)b*NN + n0 + r)*CC + h*HD + c4;
      *(float4*)&KE[r*MATP + c4] = *(const float4*)&K[g];
      *(float4*)&Vc[r*MATP + c4] = *(const float4*)&V[g];
    }
    __syncthreads();
    float z[4][4];
#pragma unroll
    for (int i = 0; i < 4; ++i)
#pragma unroll
      for (int j = 0; j < 4; ++j) z[i][j] = 0.f;
#pragma unroll 4
    for (int kk = 0; kk < 16; ++kk) {
      float4 a[4], bb[4];
#pragma unroll
      for (int il = 0; il < 4; ++il) a[il] = *(const float4*)&qs[(ti+16*il)*MATP + 4*kk];
#pragma unroll
      for (int jn = 0; jn < 4; ++jn) bb[jn] = *(const float4*)&KE[(tj+16*jn)*MATP + 4*kk];
#pragma unroll
      for (int il = 0; il < 4; ++il)
#pragma unroll
        for (int jn = 0; jn < 4; ++jn)
          z[il][jn] += a[il].x*bb[jn].x + a[il].y*bb[jn].y + a[il].z*bb[jn].z + a[il].w*bb[jn].w;
    }
    __syncthreads();
#pragma unroll
    for (int il = 0; il < 4; ++il) {
      float e0 = expf(z[il][0]), e1 = expf(z[il][1]), e2 = expf(z[il][2]), e3 = expf(z[il][3]);
      float v = shfl_sum16(e0 + e1 + e2 + e3);
      srow[il] += v;
      int rb = (ti + 16*il)*MATP + tj;
      KE[rb]      = e0;
      KE[rb + 16] = e1;
      KE[rb + 32] = e2;
      KE[rb + 48] = e3;
    }
    __syncthreads();
#pragma unroll 4
    for (int kk = 0; kk < 16; ++kk) {
      float4 a[4];
#pragma unroll
      for (int il = 0; il < 4; ++il) a[il] = *(const float4*)&KE[(ti+16*il)*MATP + 4*kk];
      float bb[4][4];
#pragma unroll
      for (int kq = 0; kq < 4; ++kq)
#pragma unroll
        for (int jn = 0; jn < 4; ++jn)
          bb[kq][jn] = Vc[(4*kk + kq)*MATP + tj + 16*jn];
#pragma unroll
      for (int il = 0; il < 4; ++il)
#pragma unroll
        for (int jn = 0; jn < 4; ++jn)
          acc[il][jn] += a[il].x*bb[0][jn] + a[il].y*bb[1][jn] + a[il].z*bb[2][jn] + a[il].w*bb[3][jn];
    }
  }
  if (tj == 0) {
#pragma unroll
    for (int il = 0; il < 4; ++il)
      atomicAdd(&S3[bh*64 + ti + 16*il], srow[il]);
  }
#pragma unroll
  for (int il = 0; il < 4; ++il)
#pragma unroll
    for (int jn = 0; jn < 4; ++jn)
      atomicAdd(&ACC3[(size_t)bh*4096 + (ti+16*il)*64 + tj + 16*jn], acc[il][jn]);
}

// ---------------- Kernel C: kernel_2 softmax + Newton-Schulz (split-bf16 MFMA) ----------------
// 256 threads = 4 waves; wave w owns C tile-row w (rows 16w..16w+15).
// Arrays (fp32, stride MATP): Arow[m][k] holds A; Scol[n][k] holds B^T (so B[k][n]=Scol[n][k]).
// mm: C = scale * A @ (FUSE ? diagc*I - B : B)
template<bool FUSE, bool HR, bool HC, bool HG>
__device__ __forceinline__ void mm_mfma(
    const float* __restrict__ Arow, const float* __restrict__ Scol,
    float diagc, float scale,
    float* __restrict__ OutRow, float* __restrict__ OutCol, float* __restrict__ OutGlob,
    int wid, int lane) {
  const int lr = lane & 15, lg = lane >> 4;
  f32x4 acc[4];
#pragma unroll
  for (int t = 0; t < 4; ++t) acc[t] = (f32x4){0.f, 0.f, 0.f, 0.f};

#pragma unroll
  for (int ks = 0; ks < 2; ++ks) {
    const int kb = ks*32 + lg*8;
    float fa[8];
    const float* ap = Arow + (wid*16 + lr)*MATP + kb;
#pragma unroll
    for (int i = 0; i < 4; ++i) { float2 t = *(const float2*)(ap + 2*i); fa[2*i] = t.x; fa[2*i+1] = t.y; }
    bf16x8 ah, al; split8(fa, ah, al);
#pragma unroll
    for (int tn = 0; tn < 4; ++tn) {
      float fb[8];
      const float* bp = Scol + (tn*16 + lr)*MATP + kb;
#pragma unroll
      for (int i = 0; i < 4; ++i) { float2 t = *(const float2*)(bp + 2*i); fb[2*i] = t.x; fb[2*i+1] = t.y; }
      if (FUSE) {
        int diff = (tn*16 + lr) - kb;   // elem i is k=kb+i; fuse diagc*I - B
#pragma unroll
        for (int i = 0; i < 8; ++i) fb[i] = (i == diff ? diagc : 0.f) - fb[i];
      }
      bf16x8 bh, bl; split8(fb, bh, bl);
      acc[tn] = __builtin_amdgcn_mfma_f32_16x16x32_bf16(ah, bh, acc[tn], 0, 0, 0);
      acc[tn] = __builtin_amdgcn_mfma_f32_16x16x32_bf16(ah, bl, acc[tn], 0, 0, 0);
      acc[tn] = __builtin_amdgcn_mfma_f32_16x16x32_bf16(al, bh, acc[tn], 0, 0, 0);
    }
  }
  __syncthreads();   // all reads done before any overwrite
#pragma unroll
  for (int tn = 0; tn < 4; ++tn) {
    float v0 = scale*acc[tn][0], v1 = scale*acc[tn][1], v2 = scale*acc[tn][2], v3 = scale*acc[tn][3];
    const int n = tn*16 + lr, m0 = wid*16 + lg*4;
    if (HC) *(float4*)&OutCol[n*MATP + m0] = make_float4(v0, v1, v2, v3);
    if (HR) {
      OutRow[(m0+0)*MATP + n] = v0;
      OutRow[(m0+1)*MATP + n] = v1;
      OutRow[(m0+2)*MATP + n] = v2;
      OutRow[(m0+3)*MATP + n] = v3;
    }
    if (HG) {
      OutGlob[(m0+0)*64 + n] = v0;
      OutGlob[(m0+1)*64 + n] = v1;
      OutGlob[(m0+2)*64 + n] = v2;
      OutGlob[(m0+3)*64 + n] = v3;
    }
  }
  __syncthreads();   // writes visible to next mm
}

__global__ __launch_bounds__(256) void inv_kernel(
    const float* __restrict__ qlm, const float* __restrict__ klm,
    const float* __restrict__ S3, const float* __restrict__ ACC3,
    float* __restrict__ W) {
  extern __shared__ float sm[];
  float* K2row = sm;
  float* Vmrow = sm + 1*MATE;
  float* Vmcol = sm + 2*MATE;
  float* Xrow  = sm + 3*MATE;
  float* Xcol  = sm + 4*MATE;
  float* Ycol  = sm + 5*MATE;
  float* Zcol  = sm + 6*MATE;
  float* red   = sm + 7*MATE;   // 1
  const int bh = blockIdx.x, tid = threadIdx.x;
  const int wid = tid >> 6, lane = tid & 63;
  const int lr = lane & 15, lg = lane >> 4;

  // stage qlm -> Xrow (A-role), klm -> Xcol (klm row-major == (klm^T) col-array)
#pragma unroll
  for (int q = 0; q < 4; ++q) {
    int f = tid + 256*q;
    int r = f >> 4, c4 = (f & 15) << 2;
    *(float4*)&Xrow[r*MATP + c4] = *(const float4*)&qlm[(size_t)bh*4096 + f*4];
    *(float4*)&Xcol[r*MATP + c4] = *(const float4*)&klm[(size_t)bh*4096 + f*4];
  }
  __syncthreads();

  // z-mm: z = qlm @ klm^T  (split-bf16 MFMA), epilogue: row-softmax -> K2row
  {
    f32x4 zacc[4];
#pragma unroll
    for (int t = 0; t < 4; ++t) zacc[t] = (f32x4){0.f, 0.f, 0.f, 0.f};
#pragma unroll
    for (int ks = 0; ks < 2; ++ks) {
      const int kb = ks*32 + lg*8;
      float fa[8];
      const float* ap = Xrow + (wid*16 + lr)*MATP + kb;
#pragma unroll
      for (int i = 0; i < 4; ++i) { float2 t = *(const float2*)(ap + 2*i); fa[2*i] = t.x; fa[2*i+1] = t.y; }
      bf16x8 ah, al; split8(fa, ah, al);
#pragma unroll
      for (int tn = 0; tn < 4; ++tn) {
        float fb[8];
        const float* bp = Xcol + (tn*16 + lr)*MATP + kb;
#pragma unroll
        for (int i = 0; i < 4; ++i) { float2 t = *(const float2*)(bp + 2*i); fb[2*i] = t.x; fb[2*i+1] = t.y; }
        bf16x8 bh, bl; split8(fb, bh, bl);
        zacc[tn] = __builtin_amdgcn_mfma_f32_16x16x32_bf16(ah, bh, zacc[tn], 0, 0, 0);
        zacc[tn] = __builtin_amdgcn_mfma_f32_16x16x32_bf16(ah, bl, zacc[tn], 0, 0, 0);
        zacc[tn] = __builtin_amdgcn_mfma_f32_16x16x32_bf16(al, bh, zacc[tn], 0, 0, 0);
      }
    }
    __syncthreads();  // done reading Xrow/Xcol (staged qlm/klm)
    float e[4][4];    // [tn][r]
#pragma unroll
    for (int tn = 0; tn < 4; ++tn)
#pragma unroll
      for (int r = 0; r < 4; ++r) e[tn][r] = expf(zacc[tn][r]);
#pragma unroll
    for (int r = 0; r < 4; ++r) {
      float t = e[0][r] + e[1][r] + e[2][r] + e[3][r];
      t = shfl_sum16(t);
      float ri = 1.0f / t;
#pragma unroll
      for (int tn = 0; tn < 4; ++tn) e[tn][r] *= ri;
    }
    const int m0 = wid*16 + lg*4;
#pragma unroll
    for (int tn = 0; tn < 4; ++tn) {
      const int n = tn*16 + lr;
#pragma unroll
      for (int r = 0; r < 4; ++r) K2row[(m0+r)*MATP + n] = e[tn][r];
    }
  }
  __syncthreads();

  // column sums -> denom = max_j ; red = 1/denom
  if (tid < 64) {
    float c = 0.f;
#pragma unroll 8
    for (int i = 0; i < 64; ++i) c += K2row[i*MATP + tid];
#pragma unroll
    for (int m = 1; m < 64; m <<= 1) c = fmaxf(c, __shfl_xor(c, m, 64));
    if (tid == 0) red[0] = 1.0f / c;
  }
  __syncthreads();
  const float invden = red[0];

  // Vm init: Vmrow = K2^T*invden (scatter), Vmcol = K2*invden (straight copy)
#pragma unroll
  for (int q = 0; q < 4; ++q) {
    int f = tid + 256*q;
    int i = f >> 4, c4 = (f & 15) << 2;
    float4 kv = *(const float4*)&K2row[i*MATP + c4];
    kv.x *= invden; kv.y *= invden; kv.z *= invden; kv.w *= invden;
    *(float4*)&Vmcol[i*MATP + c4] = kv;
    Vmrow[(c4+0)*MATP + i] = kv.x;
    Vmrow[(c4+1)*MATP + i] = kv.y;
    Vmrow[(c4+2)*MATP + i] = kv.z;
    Vmrow[(c4+3)*MATP + i] = kv.w;
  }
  __syncthreads();

  // Newton-Schulz x6
  for (int it = 0; it < 6; ++it) {
    mm_mfma<false, true,  true,  false>(K2row, Vmcol, 0.f,  1.0f,  Xrow, Xcol, nullptr, wid, lane); // X=K2@Vm
    mm_mfma<true,  false, true,  false>(Xrow,  Xcol,  7.f,  1.0f,  nullptr, Ycol, nullptr, wid, lane); // Y=X@(7I-X)
    mm_mfma<true,  false, true,  false>(Xrow,  Ycol,  15.f, 1.0f,  nullptr, Zcol, nullptr, wid, lane); // Z=X@(15I-Y)
    mm_mfma<true,  true,  true,  false>(Vmrow, Zcol,  13.f, 0.25f, Vmrow, Vmcol, nullptr, wid, lane);  // Vm'=0.25Vm@(13I-Z)
  }

  // T = ACC3/S3 staged transposed into Ycol (B-role), then W = Vm @ T -> global
#pragma unroll
  for (int q = 0; q < 4; ++q) {
    int f = tid + 256*q;
    int k = f >> 4, c4 = (f & 15) << 2;
    float4 tv = *(const float4*)&ACC3[(size_t)bh*4096 + f*4];
    float ri = 1.0f / S3[bh*64 + k];
    Ycol[(c4+0)*MATP + k] = tv.x * ri;
    Ycol[(c4+1)*MATP + k] = tv.y * ri;
    Ycol[(c4+2)*MATP + k] = tv.z * ri;
    Ycol[(c4+3)*MATP + k] = tv.w * ri;
  }
  __syncthreads();
  mm_mfma<false, false, false, true>(Vmrow, Ycol, 0.f, 1.0f, nullptr, nullptr, W + (size_t)bh*4096, wid, lane);
}

// ---------------- Kernel D: out = softmax(q k_lm^T) @ W ----------------
__global__ __launch_bounds__(256) void out_kernel(
    const float* __restrict__ Q, const float* __restrict__ klm,
    const float* __restrict__ W, float* __restrict__ Out) {
  __shared__ float QE[MATE];
  __shared__ float Kl[MATE];
  __shared__ float Ws[MATE];
  const int bh = blockIdx.y, b = bh >> 4, h = bh & 15;
  const int n0 = blockIdx.x * 64;
  const int tid = threadIdx.x, ti = tid >> 4, tj = tid & 15;

#pragma unroll
  for (int q = 0; q < 4; ++q) {
    int f = tid + 256*q;
    int r = f >> 4, c4 = (f & 15) << 2;
    float4 qv = *(const float4*)&Q[((size_t)b*NN + n0 + r)*CC + h*HD + c4];
    qv.x *= 0.125f; qv.y *= 0.125f; qv.z *= 0.125f; qv.w *= 0.125f;
    *(float4*)&QE[r*MATP + c4] = qv;
    *(float4*)&Kl[r*MATP + c4] = *(const float4*)&klm[(size_t)bh*4096 + f*4];
    *(float4*)&Ws[r*MATP + c4] = *(const float4*)&W[(size_t)bh*4096 + f*4];
  }
  __syncthreads();
  float z[4][4];
#pragma unroll
  for (int i = 0; i < 4; ++i)
#pragma unroll
    for (int j = 0; j < 4; ++j) z[i][j] = 0.f;
#pragma unroll 4
  for (int kk = 0; kk < 16; ++kk) {
    float4 a[4], bb[4];
#pragma unroll
    for (int il = 0; il < 4; ++il) a[il] = *(const float4*)&QE[(ti+16*il)*MATP + 4*kk];
#pragma unroll
    for (int jn = 0; jn < 4; ++jn) bb[jn] = *(const float4*)&Kl[(tj+16*jn)*MATP + 4*kk];
#pragma unroll
    for (int il = 0; il < 4; ++il)
#pragma unroll
      for (int jn = 0; jn < 4; ++jn)
        z[il][jn] += a[il].x*bb[jn].x + a[il].y*bb[jn].y + a[il].z*bb[jn].z + a[il].w*bb[jn].w;
  }
  __syncthreads();
#pragma unroll
  for (int il = 0; il < 4; ++il) {
    float e0 = expf(z[il][0]), e1 = expf(z[il][1]), e2 = expf(z[il][2]), e3 = expf(z[il][3]);
    float v = shfl_sum16(e0 + e1 + e2 + e3);
    float ri = 1.0f / v;
    int rb = (ti + 16*il)*MATP + tj;
    QE[rb]      = e0 * ri;
    QE[rb + 16] = e1 * ri;
    QE[rb + 32] = e2 * ri;
    QE[rb + 48] = e3 * ri;
  }
  __syncthreads();
  float o[4][4];
#pragma unroll
  for (int i = 0; i < 4; ++i)
#pragma unroll
    for (int j = 0; j < 4; ++j) o[i][j] = 0.f;
#pragma unroll 4
  for (int kk = 0; kk < 16; ++kk) {
    float4 a[4];
#pragma unroll
    for (int il = 0; il < 4; ++il) a[il] = *(const float4*)&QE[(ti+16*il)*MATP + 4*kk];
    float bb[4][4];
#pragma unroll
    for (int kq = 0; kq < 4; ++kq)
#pragma unroll
      for (int jn = 0; jn < 4; ++jn)
        bb[kq][jn] = Ws[(4*kk + kq)*MATP + tj + 16*jn];
#pragma unroll
    for (int il = 0; il < 4; ++il)
#pragma unroll
      for (int jn = 0; jn < 4; ++jn)
        o[il][jn] += a[il].x*bb[0][jn] + a[il].y*bb[1][jn] + a[il].z*bb[2][jn] + a[il].w*bb[3][jn];
  }
#pragma unroll
  for (int il = 0; il < 4; ++il)
#pragma unroll
    for (int jn = 0; jn < 4; ++jn)
      Kl[(ti+16*il)*MATP + tj + 16*jn] = o[il][jn];
  __syncthreads();
#pragma unroll
  for (int q = 0; q < 4; ++q) {
    int f = tid + 256*q;
    int r = f >> 4, c4 = (f & 15) << 2;
    *(float4*)&Out[((size_t)b*NN + n0 + r)*CC + h*HD + c4] = *(float4*)&Kl[r*MATP + c4];
  }
}

// ---------------- host ----------------
extern "C" void kernel_launch(void* const* d_in, const int* in_sizes, int n_in,
                              void* d_out, int out_size, void* d_ws, size_t ws_size,
                              hipStream_t stream) {
  const float* Q = (const float*)d_in[0];
  const float* K = (const float*)d_in[1];
  const float* V = (const float*)d_in[2];
  float* out = (float*)d_out;
  float* ws  = (float*)d_ws;

  float* qlm  = ws;               // 262144
  float* klm  = ws + 262144;      // 262144
  float* S3   = ws + 524288;      // 4096
  float* ACC3 = ws + 528384;      // 262144
  float* Wm   = ws + 790528;      // 262144

  size_t shC = (size_t)(7*MATE + 4)*sizeof(float);   // ~122 KB
  hipFuncSetAttribute((const void*)inv_kernel,
                      hipFuncAttributeMaxDynamicSharedMemorySize, (int)shC);

  hipMemsetAsync(S3, 0, (4096 + 262144)*sizeof(float), stream);

  lm_kernel <<<dim3(16, BHN), 256, 0, stream>>>(Q, K, qlm, klm);
  k3v_kernel<<<dim3(16, BHN), 256, 0, stream>>>(K, V, qlm, S3, ACC3);
  inv_kernel<<<dim3(BHN),     256, shC, stream>>>(qlm, klm, S3, ACC3, Wm);
  out_kernel<<<dim3(64, BHN), 256, 0, stream>>>(Q, klm, Wm, out);
}

// Round 4
// 178.155 us; speedup vs baseline: 5.0094x; 1.3257x over previous
//
#include <hip/hip_runtime.h>
#include <math.h>

#define BB 4
#define NN 4096
#define CC 1024
#define HH 16
#define HD 64
#define LM 64
#define SEG 64
#define BHN (BB*HH)          // 64
#define MATP 68              // fp32 row stride: 16B-aligned rows, lane-stride 68%32=4
#define MATE (64*MATP)       // 4352 floats per 64x64 tile

typedef __attribute__((ext_vector_type(8))) short bf16x8;
typedef __attribute__((ext_vector_type(4))) float f32x4;

__device__ __forceinline__ float shfl_sum16(float v) {
  v += __shfl_xor(v, 1, 16);
  v += __shfl_xor(v, 2, 16);
  v += __shfl_xor(v, 4, 16);
  v += __shfl_xor(v, 8, 16);
  return v;
}

// split fp32 -> bf16 hi (chop) + bf16 lo (chop of residual); rel err ~2^-16
__device__ __forceinline__ void split8(const float* f, bf16x8& hi, bf16x8& lo) {
#pragma unroll
  for (int i = 0; i < 8; ++i) {
    unsigned u = __builtin_bit_cast(unsigned, f[i]);
    float hf = __builtin_bit_cast(float, u & 0xFFFF0000u);
    hi[i] = (short)(u >> 16);
    float l = f[i] - hf;
    unsigned ul = __builtin_bit_cast(unsigned, l);
    lo[i] = (short)(ul >> 16);
  }
}

__device__ __forceinline__ void load_split(const float* p, bf16x8& hi, bf16x8& lo) {
  float f[8];
#pragma unroll
  for (int i = 0; i < 4; ++i) { float2 t = *(const float2*)(p + 2*i); f[2*i] = t.x; f[2*i+1] = t.y; }
  split8(f, hi, lo);
}

// ---------------- Kernel A: landmark means ----------------
__global__ __launch_bounds__(256) void lm_kernel(
    const float* __restrict__ Q, const float* __restrict__ K,
    float* __restrict__ qlm, float* __restrict__ klm) {
  int bh = blockIdx.y; int b = bh >> 4; int h = bh & 15;
  int tid = threadIdx.x;
  int l = blockIdx.x * 4 + (tid >> 6);
  int d = tid & 63;
  const float* qbase = Q + ((size_t)b*NN + (size_t)l*SEG)*CC + h*HD + d;
  const float* kbase = K + ((size_t)b*NN + (size_t)l*SEG)*CC + h*HD + d;
  float sq = 0.f, sk = 0.f;
#pragma unroll 8
  for (int s = 0; s < SEG; ++s) {
    sq += qbase[(size_t)s*CC];
    sk += kbase[(size_t)s*CC];
  }
  qlm[(size_t)bh*4096 + l*64 + d] = sq * (1.0f/(64.0f*8.0f));  // mean then /sqrt(hd)
  klm[(size_t)bh*4096 + l*64 + d] = sk * (1.0f/64.0f);
}

// ---------------- Kernel B: partials of kernel_3 @ V (MFMA) ----------------
// grid (16, BH), block 256 = 4 waves; wave w owns output rows (landmarks) 16w..16w+15.
__global__ __launch_bounds__(256) void k3v_kernel(
    const float* __restrict__ K, const float* __restrict__ V,
    const float* __restrict__ qlm,
    float* __restrict__ S3, float* __restrict__ ACC3) {
  __shared__ float qs[MATE];     // qlm row-major (A-role GEMM1)
  __shared__ float KE[MATE];     // K tile row-major (B-role GEMM1, k=d)
  __shared__ float Vt[MATE];     // V tile transposed: Vt[d][n] (B-role GEMM2, k=n)
  __shared__ float Erow[MATE];   // E row-major (A-role GEMM2)
  const int bh = blockIdx.y, b = bh >> 4, h = bh & 15;
  const int tile = blockIdx.x, tid = threadIdx.x;
  const int wid = tid >> 6, lane = tid & 63;
  const int lr = lane & 15, lg = lane >> 4;

#pragma unroll
  for (int q = 0; q < 4; ++q) {
    int f = tid + 256*q;
    int r = f >> 4, c4 = (f & 15) << 2;
    *(float4*)&qs[r*MATP + c4] = *(const float4*)&qlm[(size_t)bh*4096 + f*4];
  }

  f32x4 acc2[4];
#pragma unroll
  for (int t = 0; t < 4; ++t) acc2[t] = (f32x4){0.f, 0.f, 0.f, 0.f};
  float srow[4] = {0.f, 0.f, 0.f, 0.f};

  for (int sub = 0; sub < 4; ++sub) {
    const int n0 = tile*256 + sub*64;
    __syncthreads();   // prev sub readers of KE/Vt/Erow done
#pragma unroll
    for (int q = 0; q < 4; ++q) {
      int f = tid + 256*q;
      int r = f >> 4, c4 = (f & 15) << 2;
      size_t g = ((size_t)b*NN + n0 + r)*CC + h*HD + c4;
      *(float4*)&KE[r*MATP + c4] = *(const float4*)&K[g];
      float4 vv = *(const float4*)&V[g];
      Vt[(c4+0)*MATP + r] = vv.x;
      Vt[(c4+1)*MATP + r] = vv.y;
      Vt[(c4+2)*MATP + r] = vv.z;
      Vt[(c4+3)*MATP + r] = vv.w;
    }
    __syncthreads();

    // GEMM1: z[l][n] = sum_d qlm[l][d] * K[n][d]
    f32x4 zacc[4];
#pragma unroll
    for (int t = 0; t < 4; ++t) zacc[t] = (f32x4){0.f, 0.f, 0.f, 0.f};
#pragma unroll
    for (int ks = 0; ks < 2; ++ks) {
      const int kb = ks*32 + lg*8;
      bf16x8 ah, al; load_split(qs + (wid*16 + lr)*MATP + kb, ah, al);
#pragma unroll
      for (int tn = 0; tn < 4; ++tn) {
        bf16x8 bh_, bl_; load_split(KE + (tn*16 + lr)*MATP + kb, bh_, bl_);
        zacc[tn] = __builtin_amdgcn_mfma_f32_16x16x32_bf16(ah, bh_, zacc[tn], 0, 0, 0);
        zacc[tn] = __builtin_amdgcn_mfma_f32_16x16x32_bf16(ah, bl_, zacc[tn], 0, 0, 0);
        zacc[tn] = __builtin_amdgcn_mfma_f32_16x16x32_bf16(al, bh_, zacc[tn], 0, 0, 0);
      }
    }
    // epilogue: E = exp(z); partial row sums; E -> Erow
    float e[4][4];
#pragma unroll
    for (int tn = 0; tn < 4; ++tn)
#pragma unroll
      for (int r = 0; r < 4; ++r) e[tn][r] = expf(zacc[tn][r]);
#pragma unroll
    for (int r = 0; r < 4; ++r) {
      float t = e[0][r] + e[1][r] + e[2][r] + e[3][r];
      srow[r] += shfl_sum16(t);
    }
    const int m0 = wid*16 + lg*4;
#pragma unroll
    for (int tn = 0; tn < 4; ++tn) {
      const int n = tn*16 + lr;
#pragma unroll
      for (int r = 0; r < 4; ++r) Erow[(m0+r)*MATP + n] = e[tn][r];
    }
    __syncthreads();

    // GEMM2: acc2[l][d] += sum_n E[l][n] * V[n][d]
#pragma unroll
    for (int ks = 0; ks < 2; ++ks) {
      const int kb = ks*32 + lg*8;
      bf16x8 ah, al; load_split(Erow + (wid*16 + lr)*MATP + kb, ah, al);
#pragma unroll
      for (int tn = 0; tn < 4; ++tn) {
        bf16x8 bh_, bl_; load_split(Vt + (tn*16 + lr)*MATP + kb, bh_, bl_);
        acc2[tn] = __builtin_amdgcn_mfma_f32_16x16x32_bf16(ah, bh_, acc2[tn], 0, 0, 0);
        acc2[tn] = __builtin_amdgcn_mfma_f32_16x16x32_bf16(ah, bl_, acc2[tn], 0, 0, 0);
        acc2[tn] = __builtin_amdgcn_mfma_f32_16x16x32_bf16(al, bh_, acc2[tn], 0, 0, 0);
      }
    }
  }

  const int m0 = wid*16 + lg*4;
  if (lr == 0) {
#pragma unroll
    for (int r = 0; r < 4; ++r)
      atomicAdd(&S3[bh*64 + m0 + r], srow[r]);
  }
#pragma unroll
  for (int tn = 0; tn < 4; ++tn)
#pragma unroll
    for (int r = 0; r < 4; ++r)
      atomicAdd(&ACC3[(size_t)bh*4096 + (m0+r)*64 + tn*16 + lr], acc2[tn][r]);
}

// ---------------- Kernel C: kernel_2 softmax + Newton-Schulz (split-bf16 MFMA) ----------------
template<bool FUSE, bool HR, bool HC, bool HG>
__device__ __forceinline__ void mm_mfma(
    const float* __restrict__ Arow, const float* __restrict__ Scol,
    float diagc, float scale,
    float* __restrict__ OutRow, float* __restrict__ OutCol, float* __restrict__ OutGlob,
    int wid, int lane) {
  const int lr = lane & 15, lg = lane >> 4;
  f32x4 acc[4];
#pragma unroll
  for (int t = 0; t < 4; ++t) acc[t] = (f32x4){0.f, 0.f, 0.f, 0.f};

#pragma unroll
  for (int ks = 0; ks < 2; ++ks) {
    const int kb = ks*32 + lg*8;
    float fa[8];
    const float* ap = Arow + (wid*16 + lr)*MATP + kb;
#pragma unroll
    for (int i = 0; i < 4; ++i) { float2 t = *(const float2*)(ap + 2*i); fa[2*i] = t.x; fa[2*i+1] = t.y; }
    bf16x8 ah, al; split8(fa, ah, al);
#pragma unroll
    for (int tn = 0; tn < 4; ++tn) {
      float fb[8];
      const float* bp = Scol + (tn*16 + lr)*MATP + kb;
#pragma unroll
      for (int i = 0; i < 4; ++i) { float2 t = *(const float2*)(bp + 2*i); fb[2*i] = t.x; fb[2*i+1] = t.y; }
      if (FUSE) {
        int diff = (tn*16 + lr) - kb;
#pragma unroll
        for (int i = 0; i < 8; ++i) fb[i] = (i == diff ? diagc : 0.f) - fb[i];
      }
      bf16x8 bh_, bl_; split8(fb, bh_, bl_);
      acc[tn] = __builtin_amdgcn_mfma_f32_16x16x32_bf16(ah, bh_, acc[tn], 0, 0, 0);
      acc[tn] = __builtin_amdgcn_mfma_f32_16x16x32_bf16(ah, bl_, acc[tn], 0, 0, 0);
      acc[tn] = __builtin_amdgcn_mfma_f32_16x16x32_bf16(al, bh_, acc[tn], 0, 0, 0);
    }
  }
  __syncthreads();
#pragma unroll
  for (int tn = 0; tn < 4; ++tn) {
    float v0 = scale*acc[tn][0], v1 = scale*acc[tn][1], v2 = scale*acc[tn][2], v3 = scale*acc[tn][3];
    const int n = tn*16 + lr, m0 = wid*16 + lg*4;
    if (HC) *(float4*)&OutCol[n*MATP + m0] = make_float4(v0, v1, v2, v3);
    if (HR) {
      OutRow[(m0+0)*MATP + n] = v0;
      OutRow[(m0+1)*MATP + n] = v1;
      OutRow[(m0+2)*MATP + n] = v2;
      OutRow[(m0+3)*MATP + n] = v3;
    }
    if (HG) {
      OutGlob[(m0+0)*64 + n] = v0;
      OutGlob[(m0+1)*64 + n] = v1;
      OutGlob[(m0+2)*64 + n] = v2;
      OutGlob[(m0+3)*64 + n] = v3;
    }
  }
  __syncthreads();
}

__global__ __launch_bounds__(256) void inv_kernel(
    const float* __restrict__ qlm, const float* __restrict__ klm,
    const float* __restrict__ S3, const float* __restrict__ ACC3,
    float* __restrict__ W) {
  extern __shared__ float sm[];
  float* K2row = sm;
  float* Vmrow = sm + 1*MATE;
  float* Vmcol = sm + 2*MATE;
  float* Xrow  = sm + 3*MATE;
  float* Xcol  = sm + 4*MATE;
  float* Ycol  = sm + 5*MATE;
  float* Zcol  = sm + 6*MATE;
  float* red   = sm + 7*MATE;   // 1
  const int bh = blockIdx.x, tid = threadIdx.x;
  const int wid = tid >> 6, lane = tid & 63;
  const int lr = lane & 15, lg = lane >> 4;

#pragma unroll
  for (int q = 0; q < 4; ++q) {
    int f = tid + 256*q;
    int r = f >> 4, c4 = (f & 15) << 2;
    *(float4*)&Xrow[r*MATP + c4] = *(const float4*)&qlm[(size_t)bh*4096 + f*4];
    *(float4*)&Xcol[r*MATP + c4] = *(const float4*)&klm[(size_t)bh*4096 + f*4];
  }
  __syncthreads();

  // z = qlm @ klm^T ; softmax rows -> K2row
  {
    f32x4 zacc[4];
#pragma unroll
    for (int t = 0; t < 4; ++t) zacc[t] = (f32x4){0.f, 0.f, 0.f, 0.f};
#pragma unroll
    for (int ks = 0; ks < 2; ++ks) {
      const int kb = ks*32 + lg*8;
      bf16x8 ah, al; load_split(Xrow + (wid*16 + lr)*MATP + kb, ah, al);
#pragma unroll
      for (int tn = 0; tn < 4; ++tn) {
        bf16x8 bh_, bl_; load_split(Xcol + (tn*16 + lr)*MATP + kb, bh_, bl_);
        zacc[tn] = __builtin_amdgcn_mfma_f32_16x16x32_bf16(ah, bh_, zacc[tn], 0, 0, 0);
        zacc[tn] = __builtin_amdgcn_mfma_f32_16x16x32_bf16(ah, bl_, zacc[tn], 0, 0, 0);
        zacc[tn] = __builtin_amdgcn_mfma_f32_16x16x32_bf16(al, bh_, zacc[tn], 0, 0, 0);
      }
    }
    __syncthreads();
    float e[4][4];
#pragma unroll
    for (int tn = 0; tn < 4; ++tn)
#pragma unroll
      for (int r = 0; r < 4; ++r) e[tn][r] = expf(zacc[tn][r]);
#pragma unroll
    for (int r = 0; r < 4; ++r) {
      float t = e[0][r] + e[1][r] + e[2][r] + e[3][r];
      t = shfl_sum16(t);
      float ri = 1.0f / t;
#pragma unroll
      for (int tn = 0; tn < 4; ++tn) e[tn][r] *= ri;
    }
    const int m0 = wid*16 + lg*4;
#pragma unroll
    for (int tn = 0; tn < 4; ++tn) {
      const int n = tn*16 + lr;
#pragma unroll
      for (int r = 0; r < 4; ++r) K2row[(m0+r)*MATP + n] = e[tn][r];
    }
  }
  __syncthreads();

  if (tid < 64) {
    float c = 0.f;
#pragma unroll 8
    for (int i = 0; i < 64; ++i) c += K2row[i*MATP + tid];
#pragma unroll
    for (int m = 1; m < 64; m <<= 1) c = fmaxf(c, __shfl_xor(c, m, 64));
    if (tid == 0) red[0] = 1.0f / c;
  }
  __syncthreads();
  const float invden = red[0];

#pragma unroll
  for (int q = 0; q < 4; ++q) {
    int f = tid + 256*q;
    int i = f >> 4, c4 = (f & 15) << 2;
    float4 kv = *(const float4*)&K2row[i*MATP + c4];
    kv.x *= invden; kv.y *= invden; kv.z *= invden; kv.w *= invden;
    *(float4*)&Vmcol[i*MATP + c4] = kv;
    Vmrow[(c4+0)*MATP + i] = kv.x;
    Vmrow[(c4+1)*MATP + i] = kv.y;
    Vmrow[(c4+2)*MATP + i] = kv.z;
    Vmrow[(c4+3)*MATP + i] = kv.w;
  }
  __syncthreads();

  for (int it = 0; it < 6; ++it) {
    mm_mfma<false, true,  true,  false>(K2row, Vmcol, 0.f,  1.0f,  Xrow, Xcol, nullptr, wid, lane);
    mm_mfma<true,  false, true,  false>(Xrow,  Xcol,  7.f,  1.0f,  nullptr, Ycol, nullptr, wid, lane);
    mm_mfma<true,  false, true,  false>(Xrow,  Ycol,  15.f, 1.0f,  nullptr, Zcol, nullptr, wid, lane);
    mm_mfma<true,  true,  true,  false>(Vmrow, Zcol,  13.f, 0.25f, Vmrow, Vmcol, nullptr, wid, lane);
  }

#pragma unroll
  for (int q = 0; q < 4; ++q) {
    int f = tid + 256*q;
    int k = f >> 4, c4 = (f & 15) << 2;
    float4 tv = *(const float4*)&ACC3[(size_t)bh*4096 + f*4];
    float ri = 1.0f / S3[bh*64 + k];
    Ycol[(c4+0)*MATP + k] = tv.x * ri;
    Ycol[(c4+1)*MATP + k] = tv.y * ri;
    Ycol[(c4+2)*MATP + k] = tv.z * ri;
    Ycol[(c4+3)*MATP + k] = tv.w * ri;
  }
  __syncthreads();
  mm_mfma<false, false, false, true>(Vmrow, Ycol, 0.f, 1.0f, nullptr, nullptr, W + (size_t)bh*4096, wid, lane);
}

// ---------------- Kernel D: out = softmax(q k_lm^T) @ W  (MFMA) ----------------
__global__ __launch_bounds__(256) void out_kernel(
    const float* __restrict__ Q, const float* __restrict__ klm,
    const float* __restrict__ W, float* __restrict__ Out) {
  __shared__ float Qs[MATE];    // Q tile row-major, pre-scaled (A-role GEMM1)
  __shared__ float Kl[MATE];    // klm row-major (B-role GEMM1, k=d)
  __shared__ float Wt[MATE];    // W transposed: Wt[d][l] (B-role GEMM2, k=l)
  __shared__ float Prow[MATE];  // P row-major (A-role GEMM2)
  const int bh = blockIdx.y, b = bh >> 4, h = bh & 15;
  const int n0 = blockIdx.x * 64;
  const int tid = threadIdx.x;
  const int wid = tid >> 6, lane = tid & 63;
  const int lr = lane & 15, lg = lane >> 4;

#pragma unroll
  for (int q = 0; q < 4; ++q) {
    int f = tid + 256*q;
    int r = f >> 4, c4 = (f & 15) << 2;
    float4 qv = *(const float4*)&Q[((size_t)b*NN + n0 + r)*CC + h*HD + c4];
    qv.x *= 0.125f; qv.y *= 0.125f; qv.z *= 0.125f; qv.w *= 0.125f;
    *(float4*)&Qs[r*MATP + c4] = qv;
    *(float4*)&Kl[r*MATP + c4] = *(const float4*)&klm[(size_t)bh*4096 + f*4];
    float4 wv = *(const float4*)&W[(size_t)bh*4096 + f*4];
    Wt[(c4+0)*MATP + r] = wv.x;
    Wt[(c4+1)*MATP + r] = wv.y;
    Wt[(c4+2)*MATP + r] = wv.z;
    Wt[(c4+3)*MATP + r] = wv.w;
  }
  __syncthreads();

  // GEMM1: z[n][l] = sum_d Qs[n][d] * klm[l][d]
  f32x4 zacc[4];
#pragma unroll
  for (int t = 0; t < 4; ++t) zacc[t] = (f32x4){0.f, 0.f, 0.f, 0.f};
#pragma unroll
  for (int ks = 0; ks < 2; ++ks) {
    const int kb = ks*32 + lg*8;
    bf16x8 ah, al; load_split(Qs + (wid*16 + lr)*MATP + kb, ah, al);
#pragma unroll
    for (int tn = 0; tn < 4; ++tn) {
      bf16x8 bh_, bl_; load_split(Kl + (tn*16 + lr)*MATP + kb, bh_, bl_);
      zacc[tn] = __builtin_amdgcn_mfma_f32_16x16x32_bf16(ah, bh_, zacc[tn], 0, 0, 0);
      zacc[tn] = __builtin_amdgcn_mfma_f32_16x16x32_bf16(ah, bl_, zacc[tn], 0, 0, 0);
      zacc[tn] = __builtin_amdgcn_mfma_f32_16x16x32_bf16(al, bh_, zacc[tn], 0, 0, 0);
    }
  }
  // softmax rows -> Prow
  float e[4][4];
#pragma unroll
  for (int tn = 0; tn < 4; ++tn)
#pragma unroll
    for (int r = 0; r < 4; ++r) e[tn][r] = expf(zacc[tn][r]);
#pragma unroll
  for (int r = 0; r < 4; ++r) {
    float t = e[0][r] + e[1][r] + e[2][r] + e[3][r];
    t = shfl_sum16(t);
    float ri = 1.0f / t;
#pragma unroll
    for (int tn = 0; tn < 4; ++tn) e[tn][r] *= ri;
  }
  const int m0 = wid*16 + lg*4;
#pragma unroll
  for (int tn = 0; tn < 4; ++tn) {
    const int n = tn*16 + lr;
#pragma unroll
    for (int r = 0; r < 4; ++r) Prow[(m0+r)*MATP + n] = e[tn][r];
  }
  __syncthreads();

  // GEMM2: o[n][d] = sum_l P[n][l] * W[l][d]
  f32x4 oacc[4];
#pragma unroll
  for (int t = 0; t < 4; ++t) oacc[t] = (f32x4){0.f, 0.f, 0.f, 0.f};
#pragma unroll
  for (int ks = 0; ks < 2; ++ks) {
    const int kb = ks*32 + lg*8;
    bf16x8 ah, al; load_split(Prow + (wid*16 + lr)*MATP + kb, ah, al);
#pragma unroll
    for (int tn = 0; tn < 4; ++tn) {
      bf16x8 bh_, bl_; load_split(Wt + (tn*16 + lr)*MATP + kb, bh_, bl_);
      oacc[tn] = __builtin_amdgcn_mfma_f32_16x16x32_bf16(ah, bh_, oacc[tn], 0, 0, 0);
      oacc[tn] = __builtin_amdgcn_mfma_f32_16x16x32_bf16(ah, bl_, oacc[tn], 0, 0, 0);
      oacc[tn] = __builtin_amdgcn_mfma_f32_16x16x32_bf16(al, bh_, oacc[tn], 0, 0, 0);
    }
  }
  // store: row n0+m0+r, col h*64 + tn*16+lr
#pragma unroll
  for (int tn = 0; tn < 4; ++tn) {
    const int d = tn*16 + lr;
#pragma unroll
    for (int r = 0; r < 4; ++r)
      Out[((size_t)b*NN + n0 + m0 + r)*CC + h*HD + d] = oacc[tn][r];
  }
}

// ---------------- host ----------------
extern "C" void kernel_launch(void* const* d_in, const int* in_sizes, int n_in,
                              void* d_out, int out_size, void* d_ws, size_t ws_size,
                              hipStream_t stream) {
  const float* Q = (const float*)d_in[0];
  const float* K = (const float*)d_in[1];
  const float* V = (const float*)d_in[2];
  float* out = (float*)d_out;
  float* ws  = (float*)d_ws;

  float* qlm  = ws;               // 262144
  float* klm  = ws + 262144;      // 262144
  float* S3   = ws + 524288;      // 4096
  float* ACC3 = ws + 528384;      // 262144
  float* Wm   = ws + 790528;      // 262144

  size_t shC = (size_t)(7*MATE + 4)*sizeof(float);   // ~122 KB
  hipFuncSetAttribute((const void*)inv_kernel,
                      hipFuncAttributeMaxDynamicSharedMemorySize, (int)shC);

  hipMemsetAsync(S3, 0, (4096 + 262144)*sizeof(float), stream);

  lm_kernel <<<dim3(16, BHN), 256, 0, stream>>>(Q, K, qlm, klm);
  k3v_kernel<<<dim3(16, BHN), 256, 0, stream>>>(K, V, qlm, S3, ACC3);
  inv_kernel<<<dim3(BHN),     256, shC, stream>>>(qlm, klm, S3, ACC3, Wm);
  out_kernel<<<dim3(64, BHN), 256, 0, stream>>>(Q, klm, Wm, out);
}

// Round 5
// 171.705 us; speedup vs baseline: 5.1975x; 1.0376x over previous
//
#include <hip/hip_runtime.h>
#include <math.h>

#define BB 4
#define NN 4096
#define CC 1024
#define HH 16
#define HD 64
#define LM 64
#define SEG 64
#define BHN (BB*HH)          // 64
#define MATP 68              // fp32 row stride (inv_kernel + Erow/Prow)
#define MATE (64*MATP)
#define KS 68                // bf16-plane row stride in shorts (136 B)

typedef __attribute__((ext_vector_type(8))) short bf16x8;
typedef __attribute__((ext_vector_type(4))) short s16x4;
typedef __attribute__((ext_vector_type(4))) float f32x4;

__device__ __forceinline__ float shfl_sum16(float v) {
  v += __shfl_xor(v, 1, 16);
  v += __shfl_xor(v, 2, 16);
  v += __shfl_xor(v, 4, 16);
  v += __shfl_xor(v, 8, 16);
  return v;
}

// split fp32 -> bf16 hi (chop) + bf16 lo (chop of residual); rel err ~2^-16
__device__ __forceinline__ void split8(const float* f, bf16x8& hi, bf16x8& lo) {
#pragma unroll
  for (int i = 0; i < 8; ++i) {
    unsigned u = __builtin_bit_cast(unsigned, f[i]);
    float hf = __builtin_bit_cast(float, u & 0xFFFF0000u);
    hi[i] = (short)(u >> 16);
    float l = f[i] - hf;
    unsigned ul = __builtin_bit_cast(unsigned, l);
    lo[i] = (short)(ul >> 16);
  }
}

__device__ __forceinline__ void split4(const float* f, s16x4& hi, s16x4& lo) {
#pragma unroll
  for (int i = 0; i < 4; ++i) {
    unsigned u = __builtin_bit_cast(unsigned, f[i]);
    float hf = __builtin_bit_cast(float, u & 0xFFFF0000u);
    hi[i] = (short)(u >> 16);
    float l = f[i] - hf;
    unsigned ul = __builtin_bit_cast(unsigned, l);
    lo[i] = (short)(ul >> 16);
  }
}

// read 8 consecutive shorts (row-major plane, stride KS) as bf16x8 via 2x b64
__device__ __forceinline__ bf16x8 ld8(const short* __restrict__ P, int row, int kb) {
  s16x4 a = *(const s16x4*)&P[row*KS + kb];
  s16x4 b = *(const s16x4*)&P[row*KS + kb + 4];
  bf16x8 r;
  r[0]=a[0]; r[1]=a[1]; r[2]=a[2]; r[3]=a[3];
  r[4]=b[0]; r[5]=b[1]; r[6]=b[2]; r[7]=b[3];
  return r;
}

// read 8 shorts from a swizzled transposed plane: element (row, k) at
// byte row*136 + ((2*(k&~3)) ^ ((row&15)<<3)) + 2*(k&3)
__device__ __forceinline__ bf16x8 ldT8(const short* __restrict__ P, int row, int kb, int sw) {
  const char* base = (const char*)P + row*136;
  s16x4 a = *(const s16x4*)(base + ((2*kb) ^ sw));
  s16x4 b = *(const s16x4*)(base + ((2*kb + 8) ^ sw));
  bf16x8 r;
  r[0]=a[0]; r[1]=a[1]; r[2]=a[2]; r[3]=a[3];
  r[4]=b[0]; r[5]=b[1]; r[6]=b[2]; r[7]=b[3];
  return r;
}

// in-wave 4x4 transpose among lanes {l, l^16, l^32, l^48}
__device__ __forceinline__ void xpose4(float x[4], int lane) {
  bool p1 = (lane >> 4) & 1;
  float s0 = p1 ? x[0] : x[1], s1 = p1 ? x[2] : x[3];
  float r0 = __shfl_xor(s0, 16, 64), r1 = __shfl_xor(s1, 16, 64);
  if (p1) { x[0] = r0; x[2] = r1; } else { x[1] = r0; x[3] = r1; }
  bool p2 = (lane >> 5) & 1;
  s0 = p2 ? x[0] : x[2]; s1 = p2 ? x[1] : x[3];
  r0 = __shfl_xor(s0, 32, 64); r1 = __shfl_xor(s1, 32, 64);
  if (p2) { x[0] = r0; x[1] = r1; } else { x[2] = r0; x[3] = r1; }
}

// ---------------- Kernel A: landmark means ----------------
__global__ __launch_bounds__(256) void lm_kernel(
    const float* __restrict__ Q, const float* __restrict__ K,
    float* __restrict__ qlm, float* __restrict__ klm) {
  int bh = blockIdx.y; int b = bh >> 4; int h = bh & 15;
  int tid = threadIdx.x;
  int l = blockIdx.x * 4 + (tid >> 6);
  int d = tid & 63;
  const float* qbase = Q + ((size_t)b*NN + (size_t)l*SEG)*CC + h*HD + d;
  const float* kbase = K + ((size_t)b*NN + (size_t)l*SEG)*CC + h*HD + d;
  float sq = 0.f, sk = 0.f;
#pragma unroll 8
  for (int s = 0; s < SEG; ++s) {
    sq += qbase[(size_t)s*CC];
    sk += kbase[(size_t)s*CC];
  }
  qlm[(size_t)bh*4096 + l*64 + d] = sq * (1.0f/(64.0f*8.0f));
  klm[(size_t)bh*4096 + l*64 + d] = sk * (1.0f/64.0f);
}

// ---------------- Kernel B: partials of kernel_3 @ V (MFMA, bf16-plane LDS) ----------------
__global__ __launch_bounds__(256, 3) void k3v_kernel(
    const float* __restrict__ K, const float* __restrict__ V,
    const float* __restrict__ qlm,
    float* __restrict__ S3, float* __restrict__ ACC3) {
  __shared__ short KEh[64*KS], KEl[64*KS];   // K tile planes, row-major [n][d]
  __shared__ short VtH[64*KS], VtL[64*KS];   // V^T planes, swizzled [d][n]
  __shared__ float Erow[64*MATP];            // E fp32 row-major [l][n]
  const int bh = blockIdx.y, b = bh >> 4, h = bh & 15;
  const int tile = blockIdx.x, tid = threadIdx.x;
  const int wid = tid >> 6, lane = tid & 63;
  const int lr = lane & 15, lg = lane >> 4;
  const int m0 = wid*16 + lg*4;

  // q_lm A-fragments -> registers (split once)
  bf16x8 qh[2], ql[2];
#pragma unroll
  for (int ks = 0; ks < 2; ++ks) {
    const float* qp = qlm + (size_t)bh*4096 + (wid*16 + lr)*64 + ks*32 + lg*8;
    float qf[8];
    *(float4*)&qf[0] = *(const float4*)qp;
    *(float4*)&qf[4] = *(const float4*)(qp + 4);
    split8(qf, qh[ks], ql[ks]);
  }

  f32x4 acc2[4];
#pragma unroll
  for (int t = 0; t < 4; ++t) acc2[t] = (f32x4){0.f, 0.f, 0.f, 0.f};
  float srow[4] = {0.f, 0.f, 0.f, 0.f};

  for (int sub = 0; sub < 4; ++sub) {
    const int n0 = tile*256 + sub*64;
    __syncthreads();   // prev-sub readers of KE/Vt done
    // ---- stage: K -> KE planes (row-major), V -> Vt planes (transposed, swizzled)
#pragma unroll
    for (int q = 0; q < 4; ++q) {
      int f = tid + 256*q;
      int r = f >> 4, c4 = (f & 15) << 2;
      size_t g = ((size_t)b*NN + n0 + r)*CC + h*HD + c4;
      float4 kv = *(const float4*)&K[g];
      s16x4 kh, kl; split4((const float*)&kv, kh, kl);
      *(s16x4*)&KEh[r*KS + c4] = kh;
      *(s16x4*)&KEl[r*KS + c4] = kl;
      float4 vv = *(const float4*)&V[g];
      float x[4] = {vv.x, vv.y, vv.z, vv.w};
      xpose4(x, lane);
      int d = 4*(lane & 15) + (lane >> 4);        // column this lane owns
      int nb = 16*q + 4*wid;                      // 4 consecutive n values
      s16x4 vh, vl; split4(x, vh, vl);
      char* pv = (char*)VtH + d*136 + ((2*nb) ^ ((d & 15) << 3));
      char* pl = (char*)VtL + d*136 + ((2*nb) ^ ((d & 15) << 3));
      *(s16x4*)pv = vh;
      *(s16x4*)pl = vl;
    }
    __syncthreads();

    // ---- GEMM1: z[l][n] = sum_d qlm[l][d] * K[n][d]
    f32x4 zacc[4];
#pragma unroll
    for (int t = 0; t < 4; ++t) zacc[t] = (f32x4){0.f, 0.f, 0.f, 0.f};
#pragma unroll
    for (int ks = 0; ks < 2; ++ks) {
      const int kb = ks*32 + lg*8;
#pragma unroll
      for (int tn = 0; tn < 4; ++tn) {
        bf16x8 bh_ = ld8(KEh, tn*16 + lr, kb);
        bf16x8 bl_ = ld8(KEl, tn*16 + lr, kb);
        zacc[tn] = __builtin_amdgcn_mfma_f32_16x16x32_bf16(qh[ks], bh_, zacc[tn], 0, 0, 0);
        zacc[tn] = __builtin_amdgcn_mfma_f32_16x16x32_bf16(qh[ks], bl_, zacc[tn], 0, 0, 0);
        zacc[tn] = __builtin_amdgcn_mfma_f32_16x16x32_bf16(ql[ks], bh_, zacc[tn], 0, 0, 0);
      }
    }
    // ---- epilogue: E = exp(z); row-sum partials; E -> own rows of Erow (no barrier)
    float e[4][4];
#pragma unroll
    for (int tn = 0; tn < 4; ++tn)
#pragma unroll
      for (int r = 0; r < 4; ++r) e[tn][r] = expf(zacc[tn][r]);
#pragma unroll
    for (int r = 0; r < 4; ++r) {
      float t = e[0][r] + e[1][r] + e[2][r] + e[3][r];
      srow[r] += shfl_sum16(t);
    }
#pragma unroll
    for (int tn = 0; tn < 4; ++tn) {
      const int n = tn*16 + lr;
#pragma unroll
      for (int r = 0; r < 4; ++r) Erow[(m0 + r)*MATP + n] = e[tn][r];
    }

    // ---- GEMM2: acc2[l][d] += sum_n E[l][n] * V[n][d]
#pragma unroll
    for (int ks = 0; ks < 2; ++ks) {
      const int kb = ks*32 + lg*8;
      float fa[8];
      const float* ap = Erow + (wid*16 + lr)*MATP + kb;
      *(float4*)&fa[0] = *(const float4*)ap;
      *(float4*)&fa[4] = *(const float4*)(ap + 4);
      bf16x8 ah, al; split8(fa, ah, al);
      const int sw = lr << 3;
#pragma unroll
      for (int tn = 0; tn < 4; ++tn) {
        bf16x8 bh_ = ldT8(VtH, tn*16 + lr, kb, sw);
        bf16x8 bl_ = ldT8(VtL, tn*16 + lr, kb, sw);
        acc2[tn] = __builtin_amdgcn_mfma_f32_16x16x32_bf16(ah, bh_, acc2[tn], 0, 0, 0);
        acc2[tn] = __builtin_amdgcn_mfma_f32_16x16x32_bf16(ah, bl_, acc2[tn], 0, 0, 0);
        acc2[tn] = __builtin_amdgcn_mfma_f32_16x16x32_bf16(al, bh_, acc2[tn], 0, 0, 0);
      }
    }
  }

  if (lr == 0) {
#pragma unroll
    for (int r = 0; r < 4; ++r)
      atomicAdd(&S3[bh*64 + m0 + r], srow[r]);
  }
#pragma unroll
  for (int tn = 0; tn < 4; ++tn)
#pragma unroll
    for (int r = 0; r < 4; ++r)
      atomicAdd(&ACC3[(size_t)bh*4096 + (m0 + r)*64 + tn*16 + lr], acc2[tn][r]);
}

// ---------------- Kernel C: kernel_2 softmax + Newton-Schulz (split-bf16 MFMA) ----------------
template<bool FUSE, bool HR, bool HC, bool HG>
__device__ __forceinline__ void mm_mfma(
    const float* __restrict__ Arow, const float* __restrict__ Scol,
    float diagc, float scale,
    float* __restrict__ OutRow, float* __restrict__ OutCol, float* __restrict__ OutGlob,
    int wid, int lane) {
  const int lr = lane & 15, lg = lane >> 4;
  f32x4 acc[4];
#pragma unroll
  for (int t = 0; t < 4; ++t) acc[t] = (f32x4){0.f, 0.f, 0.f, 0.f};

#pragma unroll
  for (int ks = 0; ks < 2; ++ks) {
    const int kb = ks*32 + lg*8;
    float fa[8];
    const float* ap = Arow + (wid*16 + lr)*MATP + kb;
#pragma unroll
    for (int i = 0; i < 4; ++i) { float2 t = *(const float2*)(ap + 2*i); fa[2*i] = t.x; fa[2*i+1] = t.y; }
    bf16x8 ah, al; split8(fa, ah, al);
#pragma unroll
    for (int tn = 0; tn < 4; ++tn) {
      float fb[8];
      const float* bp = Scol + (tn*16 + lr)*MATP + kb;
#pragma unroll
      for (int i = 0; i < 4; ++i) { float2 t = *(const float2*)(bp + 2*i); fb[2*i] = t.x; fb[2*i+1] = t.y; }
      if (FUSE) {
        int diff = (tn*16 + lr) - kb;
#pragma unroll
        for (int i = 0; i < 8; ++i) fb[i] = (i == diff ? diagc : 0.f) - fb[i];
      }
      bf16x8 bh_, bl_; split8(fb, bh_, bl_);
      acc[tn] = __builtin_amdgcn_mfma_f32_16x16x32_bf16(ah, bh_, acc[tn], 0, 0, 0);
      acc[tn] = __builtin_amdgcn_mfma_f32_16x16x32_bf16(ah, bl_, acc[tn], 0, 0, 0);
      acc[tn] = __builtin_amdgcn_mfma_f32_16x16x32_bf16(al, bh_, acc[tn], 0, 0, 0);
    }
  }
  __syncthreads();
#pragma unroll
  for (int tn = 0; tn < 4; ++tn) {
    float v0 = scale*acc[tn][0], v1 = scale*acc[tn][1], v2 = scale*acc[tn][2], v3 = scale*acc[tn][3];
    const int n = tn*16 + lr, m0 = wid*16 + lg*4;
    if (HC) *(float4*)&OutCol[n*MATP + m0] = make_float4(v0, v1, v2, v3);
    if (HR) {
      OutRow[(m0+0)*MATP + n] = v0;
      OutRow[(m0+1)*MATP + n] = v1;
      OutRow[(m0+2)*MATP + n] = v2;
      OutRow[(m0+3)*MATP + n] = v3;
    }
    if (HG) {
      OutGlob[(m0+0)*64 + n] = v0;
      OutGlob[(m0+1)*64 + n] = v1;
      OutGlob[(m0+2)*64 + n] = v2;
      OutGlob[(m0+3)*64 + n] = v3;
    }
  }
  __syncthreads();
}

__global__ __launch_bounds__(256) void inv_kernel(
    const float* __restrict__ qlm, const float* __restrict__ klm,
    const float* __restrict__ S3, const float* __restrict__ ACC3,
    float* __restrict__ W) {
  extern __shared__ float sm[];
  float* K2row = sm;
  float* Vmrow = sm + 1*MATE;
  float* Vmcol = sm + 2*MATE;
  float* Xrow  = sm + 3*MATE;
  float* Xcol  = sm + 4*MATE;
  float* Ycol  = sm + 5*MATE;
  float* Zcol  = sm + 6*MATE;
  float* red   = sm + 7*MATE;   // 1
  const int bh = blockIdx.x, tid = threadIdx.x;
  const int wid = tid >> 6, lane = tid & 63;
  const int lr = lane & 15, lg = lane >> 4;

#pragma unroll
  for (int q = 0; q < 4; ++q) {
    int f = tid + 256*q;
    int r = f >> 4, c4 = (f & 15) << 2;
    *(float4*)&Xrow[r*MATP + c4] = *(const float4*)&qlm[(size_t)bh*4096 + f*4];
    *(float4*)&Xcol[r*MATP + c4] = *(const float4*)&klm[(size_t)bh*4096 + f*4];
  }
  __syncthreads();

  {
    f32x4 zacc[4];
#pragma unroll
    for (int t = 0; t < 4; ++t) zacc[t] = (f32x4){0.f, 0.f, 0.f, 0.f};
#pragma unroll
    for (int ks = 0; ks < 2; ++ks) {
      const int kb = ks*32 + lg*8;
      float fa[8];
      const float* ap = Xrow + (wid*16 + lr)*MATP + kb;
#pragma unroll
      for (int i = 0; i < 4; ++i) { float2 t = *(const float2*)(ap + 2*i); fa[2*i] = t.x; fa[2*i+1] = t.y; }
      bf16x8 ah, al; split8(fa, ah, al);
#pragma unroll
      for (int tn = 0; tn < 4; ++tn) {
        float fb[8];
        const float* bp = Xcol + (tn*16 + lr)*MATP + kb;
#pragma unroll
        for (int i = 0; i < 4; ++i) { float2 t = *(const float2*)(bp + 2*i); fb[2*i] = t.x; fb[2*i+1] = t.y; }
        bf16x8 bh_, bl_; split8(fb, bh_, bl_);
        zacc[tn] = __builtin_amdgcn_mfma_f32_16x16x32_bf16(ah, bh_, zacc[tn], 0, 0, 0);
        zacc[tn] = __builtin_amdgcn_mfma_f32_16x16x32_bf16(ah, bl_, zacc[tn], 0, 0, 0);
        zacc[tn] = __builtin_amdgcn_mfma_f32_16x16x32_bf16(al, bh_, zacc[tn], 0, 0, 0);
      }
    }
    __syncthreads();
    float e[4][4];
#pragma unroll
    for (int tn = 0; tn < 4; ++tn)
#pragma unroll
      for (int r = 0; r < 4; ++r) e[tn][r] = expf(zacc[tn][r]);
#pragma unroll
    for (int r = 0; r < 4; ++r) {
      float t = e[0][r] + e[1][r] + e[2][r] + e[3][r];
      t = shfl_sum16(t);
      float ri = 1.0f / t;
#pragma unroll
      for (int tn = 0; tn < 4; ++tn) e[tn][r] *= ri;
    }
    const int m0 = wid*16 + lg*4;
#pragma unroll
    for (int tn = 0; tn < 4; ++tn) {
      const int n = tn*16 + lr;
#pragma unroll
      for (int r = 0; r < 4; ++r) K2row[(m0+r)*MATP + n] = e[tn][r];
    }
  }
  __syncthreads();

  if (tid < 64) {
    float c = 0.f;
#pragma unroll 8
    for (int i = 0; i < 64; ++i) c += K2row[i*MATP + tid];
#pragma unroll
    for (int m = 1; m < 64; m <<= 1) c = fmaxf(c, __shfl_xor(c, m, 64));
    if (tid == 0) red[0] = 1.0f / c;
  }
  __syncthreads();
  const float invden = red[0];

#pragma unroll
  for (int q = 0; q < 4; ++q) {
    int f = tid + 256*q;
    int i = f >> 4, c4 = (f & 15) << 2;
    float4 kv = *(const float4*)&K2row[i*MATP + c4];
    kv.x *= invden; kv.y *= invden; kv.z *= invden; kv.w *= invden;
    *(float4*)&Vmcol[i*MATP + c4] = kv;
    Vmrow[(c4+0)*MATP + i] = kv.x;
    Vmrow[(c4+1)*MATP + i] = kv.y;
    Vmrow[(c4+2)*MATP + i] = kv.z;
    Vmrow[(c4+3)*MATP + i] = kv.w;
  }
  __syncthreads();

  for (int it = 0; it < 6; ++it) {
    mm_mfma<false, true,  true,  false>(K2row, Vmcol, 0.f,  1.0f,  Xrow, Xcol, nullptr, wid, lane);
    mm_mfma<true,  false, true,  false>(Xrow,  Xcol,  7.f,  1.0f,  nullptr, Ycol, nullptr, wid, lane);
    mm_mfma<true,  false, true,  false>(Xrow,  Ycol,  15.f, 1.0f,  nullptr, Zcol, nullptr, wid, lane);
    mm_mfma<true,  true,  true,  false>(Vmrow, Zcol,  13.f, 0.25f, Vmrow, Vmcol, nullptr, wid, lane);
  }

#pragma unroll
  for (int q = 0; q < 4; ++q) {
    int f = tid + 256*q;
    int k = f >> 4, c4 = (f & 15) << 2;
    float4 tv = *(const float4*)&ACC3[(size_t)bh*4096 + f*4];
    float ri = 1.0f / S3[bh*64 + k];
    Ycol[(c4+0)*MATP + k] = tv.x * ri;
    Ycol[(c4+1)*MATP + k] = tv.y * ri;
    Ycol[(c4+2)*MATP + k] = tv.z * ri;
    Ycol[(c4+3)*MATP + k] = tv.w * ri;
  }
  __syncthreads();
  mm_mfma<false, false, false, true>(Vmrow, Ycol, 0.f, 1.0f, nullptr, nullptr, W + (size_t)bh*4096, wid, lane);
}

// ---------------- Kernel D: out = softmax(q k_lm^T) @ W  (bf16-plane LDS) ----------------
__global__ __launch_bounds__(256, 3) void out_kernel(
    const float* __restrict__ Q, const float* __restrict__ klm,
    const float* __restrict__ W, float* __restrict__ Out) {
  __shared__ short KlH[64*KS], KlL[64*KS];   // klm planes row-major [l][d]
  __shared__ short WtH[64*KS], WtL[64*KS];   // W^T planes, swizzled [d][l]
  __shared__ float Prow[64*MATP];            // P fp32 row-major [n][l]
  const int bh = blockIdx.y, b = bh >> 4, h = bh & 15;
  const int n0 = blockIdx.x * 64;
  const int tid = threadIdx.x;
  const int wid = tid >> 6, lane = tid & 63;
  const int lr = lane & 15, lg = lane >> 4;
  const int m0 = wid*16 + lg*4;

  // stage klm + W^T (once)
#pragma unroll
  for (int q = 0; q < 4; ++q) {
    int f = tid + 256*q;
    int r = f >> 4, c4 = (f & 15) << 2;
    float4 kl = *(const float4*)&klm[(size_t)bh*4096 + f*4];
    s16x4 kh, kll; split4((const float*)&kl, kh, kll);
    *(s16x4*)&KlH[r*KS + c4] = kh;
    *(s16x4*)&KlL[r*KS + c4] = kll;
    float4 wv = *(const float4*)&W[(size_t)bh*4096 + f*4];
    float x[4] = {wv.x, wv.y, wv.z, wv.w};
    xpose4(x, lane);
    int d = 4*(lane & 15) + (lane >> 4);
    int nb = 16*q + 4*wid;
    s16x4 wh, wl; split4(x, wh, wl);
    char* pv = (char*)WtH + d*136 + ((2*nb) ^ ((d & 15) << 3));
    char* pl = (char*)WtL + d*136 + ((2*nb) ^ ((d & 15) << 3));
    *(s16x4*)pv = wh;
    *(s16x4*)pl = wl;
  }

  // Q A-fragments -> registers (scaled, split once)
  bf16x8 qh[2], ql[2];
#pragma unroll
  for (int ks = 0; ks < 2; ++ks) {
    const float* qp = Q + ((size_t)b*NN + n0 + wid*16 + lr)*CC + h*HD + ks*32 + lg*8;
    float qf[8];
    *(float4*)&qf[0] = *(const float4*)qp;
    *(float4*)&qf[4] = *(const float4*)(qp + 4);
#pragma unroll
    for (int i = 0; i < 8; ++i) qf[i] *= 0.125f;
    split8(qf, qh[ks], ql[ks]);
  }
  __syncthreads();

  // GEMM1: z[n][l] = sum_d Q[n][d] * klm[l][d]
  f32x4 zacc[4];
#pragma unroll
  for (int t = 0; t < 4; ++t) zacc[t] = (f32x4){0.f, 0.f, 0.f, 0.f};
#pragma unroll
  for (int ks = 0; ks < 2; ++ks) {
    const int kb = ks*32 + lg*8;
#pragma unroll
    for (int tn = 0; tn < 4; ++tn) {
      bf16x8 bh_ = ld8(KlH, tn*16 + lr, kb);
      bf16x8 bl_ = ld8(KlL, tn*16 + lr, kb);
      zacc[tn] = __builtin_amdgcn_mfma_f32_16x16x32_bf16(qh[ks], bh_, zacc[tn], 0, 0, 0);
      zacc[tn] = __builtin_amdgcn_mfma_f32_16x16x32_bf16(qh[ks], bl_, zacc[tn], 0, 0, 0);
      zacc[tn] = __builtin_amdgcn_mfma_f32_16x16x32_bf16(ql[ks], bh_, zacc[tn], 0, 0, 0);
    }
  }
  // softmax rows -> own rows of Prow (no barrier needed)
  float e[4][4];
#pragma unroll
  for (int tn = 0; tn < 4; ++tn)
#pragma unroll
    for (int r = 0; r < 4; ++r) e[tn][r] = expf(zacc[tn][r]);
#pragma unroll
  for (int r = 0; r < 4; ++r) {
    float t = e[0][r] + e[1][r] + e[2][r] + e[3][r];
    t = shfl_sum16(t);
    float ri = 1.0f / t;
#pragma unroll
    for (int tn = 0; tn < 4; ++tn) e[tn][r] *= ri;
  }
#pragma unroll
  for (int tn = 0; tn < 4; ++tn) {
    const int n = tn*16 + lr;
#pragma unroll
    for (int r = 0; r < 4; ++r) Prow[(m0+r)*MATP + n] = e[tn][r];
  }

  // GEMM2: o[n][d] = sum_l P[n][l] * W[l][d]
  f32x4 oacc[4];
#pragma unroll
  for (int t = 0; t < 4; ++t) oacc[t] = (f32x4){0.f, 0.f, 0.f, 0.f};
#pragma unroll
  for (int ks = 0; ks < 2; ++ks) {
    const int kb = ks*32 + lg*8;
    float fa[8];
    const float* ap = Prow + (wid*16 + lr)*MATP + kb;
    *(float4*)&fa[0] = *(const float4*)ap;
    *(float4*)&fa[4] = *(const float4*)(ap + 4);
    bf16x8 ah, al; split8(fa, ah, al);
    const int sw = lr << 3;
#pragma unroll
    for (int tn = 0; tn < 4; ++tn) {
      bf16x8 bh_ = ldT8(WtH, tn*16 + lr, kb, sw);
      bf16x8 bl_ = ldT8(WtL, tn*16 + lr, kb, sw);
      oacc[tn] = __builtin_amdgcn_mfma_f32_16x16x32_bf16(ah, bh_, oacc[tn], 0, 0, 0);
      oacc[tn] = __builtin_amdgcn_mfma_f32_16x16x32_bf16(ah, bl_, oacc[tn], 0, 0, 0);
      oacc[tn] = __builtin_amdgcn_mfma_f32_16x16x32_bf16(al, bh_, oacc[tn], 0, 0, 0);
    }
  }
#pragma unroll
  for (int tn = 0; tn < 4; ++tn) {
    const int d = tn*16 + lr;
#pragma unroll
    for (int r = 0; r < 4; ++r)
      Out[((size_t)b*NN + n0 + m0 + r)*CC + h*HD + d] = oacc[tn][r];
  }
}

// ---------------- host ----------------
extern "C" void kernel_launch(void* const* d_in, const int* in_sizes, int n_in,
                              void* d_out, int out_size, void* d_ws, size_t ws_size,
                              hipStream_t stream) {
  const float* Q = (const float*)d_in[0];
  const float* K = (const float*)d_in[1];
  const float* V = (const float*)d_in[2];
  float* out = (float*)d_out;
  float* ws  = (float*)d_ws;

  float* qlm  = ws;               // 262144
  float* klm  = ws + 262144;      // 262144
  float* S3   = ws + 524288;      // 4096
  float* ACC3 = ws + 528384;      // 262144
  float* Wm   = ws + 790528;      // 262144

  size_t shC = (size_t)(7*MATE + 4)*sizeof(float);   // ~122 KB
  hipFuncSetAttribute((const void*)inv_kernel,
                      hipFuncAttributeMaxDynamicSharedMemorySize, (int)shC);

  hipMemsetAsync(S3, 0, (4096 + 262144)*sizeof(float), stream);

  lm_kernel <<<dim3(16, BHN), 256, 0, stream>>>(Q, K, qlm, klm);
  k3v_kernel<<<dim3(16, BHN), 256, 0, stream>>>(K, V, qlm, S3, ACC3);
  inv_kernel<<<dim3(BHN),     256, shC, stream>>>(qlm, klm, S3, ACC3, Wm);
  out_kernel<<<dim3(64, BHN), 256, 0, stream>>>(Q, klm, Wm, out);
}

// Round 6
// 147.692 us; speedup vs baseline: 6.0426x; 1.1626x over previous
//
#include <hip/hip_runtime.h>
#include <math.h>

#define BB 4
#define NN 4096
#define CC 1024
#define HH 16
#define HD 64
#define LM 64
#define SEG 64
#define BHN (BB*HH)          // 64
#define MATP 68              // fp32 row stride (inv buffers + Erow/Prow): 272B rows, 16B-aligned
#define MATE (64*MATP)

typedef __attribute__((ext_vector_type(8))) short bf16x8;
typedef __attribute__((ext_vector_type(4))) short s16x4;
typedef __attribute__((ext_vector_type(4))) float f32x4;

__device__ __forceinline__ float shfl_sum16(float v) {
  v += __shfl_xor(v, 1, 16);
  v += __shfl_xor(v, 2, 16);
  v += __shfl_xor(v, 4, 16);
  v += __shfl_xor(v, 8, 16);
  return v;
}

// split fp32 -> bf16 hi (chop) + bf16 lo (chop of residual); rel err ~2^-16
__device__ __forceinline__ void split8(const float* f, bf16x8& hi, bf16x8& lo) {
#pragma unroll
  for (int i = 0; i < 8; ++i) {
    unsigned u = __builtin_bit_cast(unsigned, f[i]);
    float hf = __builtin_bit_cast(float, u & 0xFFFF0000u);
    hi[i] = (short)(u >> 16);
    float l = f[i] - hf;
    unsigned ul = __builtin_bit_cast(unsigned, l);
    lo[i] = (short)(ul >> 16);
  }
}

__device__ __forceinline__ void split4(const float* f, s16x4& hi, s16x4& lo) {
#pragma unroll
  for (int i = 0; i < 4; ++i) {
    unsigned u = __builtin_bit_cast(unsigned, f[i]);
    float hf = __builtin_bit_cast(float, u & 0xFFFF0000u);
    hi[i] = (short)(u >> 16);
    float l = f[i] - hf;
    unsigned ul = __builtin_bit_cast(unsigned, l);
    lo[i] = (short)(ul >> 16);
  }
}

// m214-style plane: 64 rows x 64 shorts (128B rows), byte ^= (row&7)<<4.
// One b128 per fragment (row, 16B-chunk cd).
__device__ __forceinline__ int planeAddr(int row, int cd) {
  int B = (row << 7) + (cd << 4);
  return B ^ ((row & 7) << 4);
}
__device__ __forceinline__ bf16x8 ldP(const short* __restrict__ P, int row, int cd) {
  return *(const bf16x8*)((const char*)P + planeAddr(row, cd));
}

// in-wave 4x4 transpose among lanes {l, l^16, l^32, l^48} (verified R4/R5)
__device__ __forceinline__ void xpose4(float x[4], int lane) {
  bool p1 = (lane >> 4) & 1;
  float s0 = p1 ? x[0] : x[1], s1 = p1 ? x[2] : x[3];
  float r0 = __shfl_xor(s0, 16, 64), r1 = __shfl_xor(s1, 16, 64);
  if (p1) { x[0] = r0; x[2] = r1; } else { x[1] = r0; x[3] = r1; }
  bool p2 = (lane >> 5) & 1;
  s0 = p2 ? x[0] : x[2]; s1 = p2 ? x[1] : x[3];
  r0 = __shfl_xor(s0, 32, 64); r1 = __shfl_xor(s1, 32, 64);
  if (p2) { x[0] = r0; x[1] = r1; } else { x[2] = r0; x[3] = r1; }
}

// ---------------- Kernel A: landmark means ----------------
__global__ __launch_bounds__(256) void lm_kernel(
    const float* __restrict__ Q, const float* __restrict__ K,
    float* __restrict__ qlm, float* __restrict__ klm) {
  int bh = blockIdx.y; int b = bh >> 4; int h = bh & 15;
  int tid = threadIdx.x;
  int l = blockIdx.x * 4 + (tid >> 6);
  int d = tid & 63;
  const float* qbase = Q + ((size_t)b*NN + (size_t)l*SEG)*CC + h*HD + d;
  const float* kbase = K + ((size_t)b*NN + (size_t)l*SEG)*CC + h*HD + d;
  float sq = 0.f, sk = 0.f;
#pragma unroll 8
  for (int s = 0; s < SEG; ++s) {
    sq += qbase[(size_t)s*CC];
    sk += kbase[(size_t)s*CC];
  }
  qlm[(size_t)bh*4096 + l*64 + d] = sq * (1.0f/(64.0f*8.0f));
  klm[(size_t)bh*4096 + l*64 + d] = sk * (1.0f/64.0f);
}

// ---------------- Kernel B: partials of kernel_3 @ V ----------------
// grid (32, BH): 128 n per block = 2 subs of 64, register-prefetched.
__global__ __launch_bounds__(256, 3) void k3v_kernel(
    const float* __restrict__ K, const float* __restrict__ V,
    const float* __restrict__ qlm,
    float* __restrict__ S3, float* __restrict__ ACC3) {
  __shared__ alignas(16) short KEh[64*64], KEl[64*64];  // K tile [n][d] planes
  __shared__ alignas(16) short VtH[64*64], VtL[64*64];  // V^T [d][n] planes
  __shared__ alignas(16) float Erow[64*MATP];           // E fp32 [l][n]
  const int bh = blockIdx.y, b = bh >> 4, h = bh & 15;
  const int tile = blockIdx.x, tid = threadIdx.x;
  const int wid = tid >> 6, lane = tid & 63;
  const int lr = lane & 15, lg = lane >> 4;
  const int m0 = wid*16 + lg*4;

  // q_lm A-fragments -> registers (split once)
  bf16x8 qh[2], ql[2];
#pragma unroll
  for (int ks = 0; ks < 2; ++ks) {
    const float* qp = qlm + (size_t)bh*4096 + (wid*16 + lr)*64 + ks*32 + lg*8;
    float qf[8];
    *(float4*)&qf[0] = *(const float4*)qp;
    *(float4*)&qf[4] = *(const float4*)(qp + 4);
    split8(qf, qh[ks], ql[ks]);
  }

  f32x4 acc2[4];
#pragma unroll
  for (int t = 0; t < 4; ++t) acc2[t] = (f32x4){0.f, 0.f, 0.f, 0.f};
  float srow[4] = {0.f, 0.f, 0.f, 0.f};

  // per-thread staging coords
  const int rk0 = tid >> 3,        ck = tid & 7;        // K: q2=0 row/chunk
  const int rk1 = (tid + 256) >> 3;                     // K: q2=1 row
  const int dV  = 4*lr + lg;                            // Vt row this lane owns

  float4 gk[2][2], gv[4];

#define K3V_LOAD(SUB)                                                          \
  {                                                                            \
    const int n0_ = tile*128 + (SUB)*64;                                       \
    const float* kb0 = &K[((size_t)b*NN + n0_ + rk0)*CC + h*HD + ck*8];        \
    const float* kb1 = &K[((size_t)b*NN + n0_ + rk1)*CC + h*HD + ck*8];        \
    gk[0][0] = *(const float4*)kb0;  gk[0][1] = *(const float4*)(kb0 + 4);     \
    gk[1][0] = *(const float4*)kb1;  gk[1][1] = *(const float4*)(kb1 + 4);     \
    _Pragma("unroll")                                                          \
    for (int q = 0; q < 4; ++q) {                                              \
      int f = tid + 256*q;                                                     \
      int r = f >> 4, c4 = (f & 15) << 2;                                      \
      gv[q] = *(const float4*)&V[((size_t)b*NN + n0_ + r)*CC + h*HD + c4];     \
    }                                                                          \
  }

#define K3V_WRITE()                                                            \
  {                                                                            \
    _Pragma("unroll")                                                          \
    for (int q2 = 0; q2 < 2; ++q2) {                                           \
      float kf[8];                                                             \
      *(float4*)&kf[0] = gk[q2][0];                                            \
      *(float4*)&kf[4] = gk[q2][1];                                            \
      bf16x8 khv, klv; split8(kf, khv, klv);                                   \
      int r = q2 ? rk1 : rk0;                                                  \
      int A = planeAddr(r, ck);                                                \
      *(bf16x8*)((char*)KEh + A) = khv;                                        \
      *(bf16x8*)((char*)KEl + A) = klv;                                        \
    }                                                                          \
    _Pragma("unroll")                                                          \
    for (int q = 0; q < 4; ++q) {                                              \
      float x[4] = {gv[q].x, gv[q].y, gv[q].z, gv[q].w};                       \
      xpose4(x, lane);                                                         \
      int nb = 16*q + 4*wid;                                                   \
      s16x4 vh, vl; split4(x, vh, vl);                                         \
      int B = (dV << 7) + (nb << 1);                                           \
      B ^= (dV & 7) << 4;                                                      \
      *(s16x4*)((char*)VtH + B) = vh;                                          \
      *(s16x4*)((char*)VtL + B) = vl;                                          \
    }                                                                          \
  }

#define K3V_COMPUTE()                                                          \
  {                                                                            \
    f32x4 zacc[4];                                                             \
    _Pragma("unroll")                                                          \
    for (int t = 0; t < 4; ++t) zacc[t] = (f32x4){0.f, 0.f, 0.f, 0.f};        \
    _Pragma("unroll")                                                          \
    for (int ks = 0; ks < 2; ++ks) {                                           \
      _Pragma("unroll")                                                        \
      for (int tn = 0; tn < 4; ++tn) {                                         \
        bf16x8 bh_ = ldP(KEh, tn*16 + lr, 4*ks + lg);                          \
        bf16x8 bl_ = ldP(KEl, tn*16 + lr, 4*ks + lg);                          \
        zacc[tn] = __builtin_amdgcn_mfma_f32_16x16x32_bf16(qh[ks], bh_, zacc[tn], 0, 0, 0); \
        zacc[tn] = __builtin_amdgcn_mfma_f32_16x16x32_bf16(qh[ks], bl_, zacc[tn], 0, 0, 0); \
        zacc[tn] = __builtin_amdgcn_mfma_f32_16x16x32_bf16(ql[ks], bh_, zacc[tn], 0, 0, 0); \
      }                                                                        \
    }                                                                          \
    float e[4][4];                                                             \
    _Pragma("unroll")                                                          \
    for (int tn = 0; tn < 4; ++tn)                                             \
      _Pragma("unroll")                                                        \
      for (int r = 0; r < 4; ++r) e[tn][r] = __expf(zacc[tn][r]);              \
    _Pragma("unroll")                                                          \
    for (int r = 0; r < 4; ++r) {                                              \
      float t = e[0][r] + e[1][r] + e[2][r] + e[3][r];                         \
      srow[r] += shfl_sum16(t);                                                \
    }                                                                          \
    _Pragma("unroll")                                                          \
    for (int tn = 0; tn < 4; ++tn) {                                           \
      const int n = tn*16 + lr;                                                \
      _Pragma("unroll")                                                        \
      for (int r = 0; r < 4; ++r) Erow[(m0 + r)*MATP + n] = e[tn][r];          \
    }                                                                          \
    _Pragma("unroll")                                                          \
    for (int ks = 0; ks < 2; ++ks) {                                           \
      float fa[8];                                                             \
      const float* ap = Erow + (wid*16 + lr)*MATP + ks*32 + lg*8;              \
      *(float4*)&fa[0] = *(const float4*)ap;                                   \
      *(float4*)&fa[4] = *(const float4*)(ap + 4);                             \
      bf16x8 ah, al; split8(fa, ah, al);                                       \
      _Pragma("unroll")                                                        \
      for (int tn = 0; tn < 4; ++tn) {                                         \
        bf16x8 bh_ = ldP(VtH, tn*16 + lr, 4*ks + lg);                          \
        bf16x8 bl_ = ldP(VtL, tn*16 + lr, 4*ks + lg);                          \
        acc2[tn] = __builtin_amdgcn_mfma_f32_16x16x32_bf16(ah, bh_, acc2[tn], 0, 0, 0); \
        acc2[tn] = __builtin_amdgcn_mfma_f32_16x16x32_bf16(ah, bl_, acc2[tn], 0, 0, 0); \
        acc2[tn] = __builtin_amdgcn_mfma_f32_16x16x32_bf16(al, bh_, acc2[tn], 0, 0, 0); \
      }                                                                        \
    }                                                                          \
  }

  K3V_LOAD(0)
  K3V_WRITE()
  __syncthreads();
  K3V_LOAD(1)        // in flight during sub0 compute
  K3V_COMPUTE()
  __syncthreads();
  K3V_WRITE()
  __syncthreads();
  K3V_COMPUTE()

  if (lr == 0) {
#pragma unroll
    for (int r = 0; r < 4; ++r)
      atomicAdd(&S3[bh*64 + m0 + r], srow[r]);
  }
#pragma unroll
  for (int tn = 0; tn < 4; ++tn)
#pragma unroll
    for (int r = 0; r < 4; ++r)
      atomicAdd(&ACC3[(size_t)bh*4096 + (m0 + r)*64 + tn*16 + lr], acc2[tn][r]);
}

// ---------------- Kernel C: kernel_2 softmax + Newton-Schulz (unchanged, passing) ----------------
template<bool FUSE, bool HR, bool HC, bool HG>
__device__ __forceinline__ void mm_mfma(
    const float* __restrict__ Arow, const float* __restrict__ Scol,
    float diagc, float scale,
    float* __restrict__ OutRow, float* __restrict__ OutCol, float* __restrict__ OutGlob,
    int wid, int lane) {
  const int lr = lane & 15, lg = lane >> 4;
  f32x4 acc[4];
#pragma unroll
  for (int t = 0; t < 4; ++t) acc[t] = (f32x4){0.f, 0.f, 0.f, 0.f};

#pragma unroll
  for (int ks = 0; ks < 2; ++ks) {
    const int kb = ks*32 + lg*8;
    float fa[8];
    const float* ap = Arow + (wid*16 + lr)*MATP + kb;
#pragma unroll
    for (int i = 0; i < 4; ++i) { float2 t = *(const float2*)(ap + 2*i); fa[2*i] = t.x; fa[2*i+1] = t.y; }
    bf16x8 ah, al; split8(fa, ah, al);
#pragma unroll
    for (int tn = 0; tn < 4; ++tn) {
      float fb[8];
      const float* bp = Scol + (tn*16 + lr)*MATP + kb;
#pragma unroll
      for (int i = 0; i < 4; ++i) { float2 t = *(const float2*)(bp + 2*i); fb[2*i] = t.x; fb[2*i+1] = t.y; }
      if (FUSE) {
        int diff = (tn*16 + lr) - kb;
#pragma unroll
        for (int i = 0; i < 8; ++i) fb[i] = (i == diff ? diagc : 0.f) - fb[i];
      }
      bf16x8 bh_, bl_; split8(fb, bh_, bl_);
      acc[tn] = __builtin_amdgcn_mfma_f32_16x16x32_bf16(ah, bh_, acc[tn], 0, 0, 0);
      acc[tn] = __builtin_amdgcn_mfma_f32_16x16x32_bf16(ah, bl_, acc[tn], 0, 0, 0);
      acc[tn] = __builtin_amdgcn_mfma_f32_16x16x32_bf16(al, bh_, acc[tn], 0, 0, 0);
    }
  }
  __syncthreads();
#pragma unroll
  for (int tn = 0; tn < 4; ++tn) {
    float v0 = scale*acc[tn][0], v1 = scale*acc[tn][1], v2 = scale*acc[tn][2], v3 = scale*acc[tn][3];
    const int n = tn*16 + lr, m0 = wid*16 + lg*4;
    if (HC) *(float4*)&OutCol[n*MATP + m0] = make_float4(v0, v1, v2, v3);
    if (HR) {
      OutRow[(m0+0)*MATP + n] = v0;
      OutRow[(m0+1)*MATP + n] = v1;
      OutRow[(m0+2)*MATP + n] = v2;
      OutRow[(m0+3)*MATP + n] = v3;
    }
    if (HG) {
      OutGlob[(m0+0)*64 + n] = v0;
      OutGlob[(m0+1)*64 + n] = v1;
      OutGlob[(m0+2)*64 + n] = v2;
      OutGlob[(m0+3)*64 + n] = v3;
    }
  }
  __syncthreads();
}

__global__ __launch_bounds__(256) void inv_kernel(
    const float* __restrict__ qlm, const float* __restrict__ klm,
    const float* __restrict__ S3, const float* __restrict__ ACC3,
    float* __restrict__ W) {
  extern __shared__ float sm[];
  float* K2row = sm;
  float* Vmrow = sm + 1*MATE;
  float* Vmcol = sm + 2*MATE;
  float* Xrow  = sm + 3*MATE;
  float* Xcol  = sm + 4*MATE;
  float* Ycol  = sm + 5*MATE;
  float* Zcol  = sm + 6*MATE;
  float* red   = sm + 7*MATE;   // 1
  const int bh = blockIdx.x, tid = threadIdx.x;
  const int wid = tid >> 6, lane = tid & 63;
  const int lr = lane & 15, lg = lane >> 4;

#pragma unroll
  for (int q = 0; q < 4; ++q) {
    int f = tid + 256*q;
    int r = f >> 4, c4 = (f & 15) << 2;
    *(float4*)&Xrow[r*MATP + c4] = *(const float4*)&qlm[(size_t)bh*4096 + f*4];
    *(float4*)&Xcol[r*MATP + c4] = *(const float4*)&klm[(size_t)bh*4096 + f*4];
  }
  __syncthreads();

  {
    f32x4 zacc[4];
#pragma unroll
    for (int t = 0; t < 4; ++t) zacc[t] = (f32x4){0.f, 0.f, 0.f, 0.f};
#pragma unroll
    for (int ks = 0; ks < 2; ++ks) {
      const int kb = ks*32 + lg*8;
      float fa[8];
      const float* ap = Xrow + (wid*16 + lr)*MATP + kb;
#pragma unroll
      for (int i = 0; i < 4; ++i) { float2 t = *(const float2*)(ap + 2*i); fa[2*i] = t.x; fa[2*i+1] = t.y; }
      bf16x8 ah, al; split8(fa, ah, al);
#pragma unroll
      for (int tn = 0; tn < 4; ++tn) {
        float fb[8];
        const float* bp = Xcol + (tn*16 + lr)*MATP + kb;
#pragma unroll
        for (int i = 0; i < 4; ++i) { float2 t = *(const float2*)(bp + 2*i); fb[2*i] = t.x; fb[2*i+1] = t.y; }
        bf16x8 bh_, bl_; split8(fb, bh_, bl_);
        zacc[tn] = __builtin_amdgcn_mfma_f32_16x16x32_bf16(ah, bh_, zacc[tn], 0, 0, 0);
        zacc[tn] = __builtin_amdgcn_mfma_f32_16x16x32_bf16(ah, bl_, zacc[tn], 0, 0, 0);
        zacc[tn] = __builtin_amdgcn_mfma_f32_16x16x32_bf16(al, bh_, zacc[tn], 0, 0, 0);
      }
    }
    __syncthreads();
    float e[4][4];
#pragma unroll
    for (int tn = 0; tn < 4; ++tn)
#pragma unroll
      for (int r = 0; r < 4; ++r) e[tn][r] = __expf(zacc[tn][r]);
#pragma unroll
    for (int r = 0; r < 4; ++r) {
      float t = e[0][r] + e[1][r] + e[2][r] + e[3][r];
      t = shfl_sum16(t);
      float ri = 1.0f / t;
#pragma unroll
      for (int tn = 0; tn < 4; ++tn) e[tn][r] *= ri;
    }
    const int m0 = wid*16 + lg*4;
#pragma unroll
    for (int tn = 0; tn < 4; ++tn) {
      const int n = tn*16 + lr;
#pragma unroll
      for (int r = 0; r < 4; ++r) K2row[(m0+r)*MATP + n] = e[tn][r];
    }
  }
  __syncthreads();

  if (tid < 64) {
    float c = 0.f;
#pragma unroll 8
    for (int i = 0; i < 64; ++i) c += K2row[i*MATP + tid];
#pragma unroll
    for (int m = 1; m < 64; m <<= 1) c = fmaxf(c, __shfl_xor(c, m, 64));
    if (tid == 0) red[0] = 1.0f / c;
  }
  __syncthreads();
  const float invden = red[0];

#pragma unroll
  for (int q = 0; q < 4; ++q) {
    int f = tid + 256*q;
    int i = f >> 4, c4 = (f & 15) << 2;
    float4 kv = *(const float4*)&K2row[i*MATP + c4];
    kv.x *= invden; kv.y *= invden; kv.z *= invden; kv.w *= invden;
    *(float4*)&Vmcol[i*MATP + c4] = kv;
    Vmrow[(c4+0)*MATP + i] = kv.x;
    Vmrow[(c4+1)*MATP + i] = kv.y;
    Vmrow[(c4+2)*MATP + i] = kv.z;
    Vmrow[(c4+3)*MATP + i] = kv.w;
  }
  __syncthreads();

  for (int it = 0; it < 6; ++it) {
    mm_mfma<false, true,  true,  false>(K2row, Vmcol, 0.f,  1.0f,  Xrow, Xcol, nullptr, wid, lane);
    mm_mfma<true,  false, true,  false>(Xrow,  Xcol,  7.f,  1.0f,  nullptr, Ycol, nullptr, wid, lane);
    mm_mfma<true,  false, true,  false>(Xrow,  Ycol,  15.f, 1.0f,  nullptr, Zcol, nullptr, wid, lane);
    mm_mfma<true,  true,  true,  false>(Vmrow, Zcol,  13.f, 0.25f, Vmrow, Vmcol, nullptr, wid, lane);
  }

#pragma unroll
  for (int q = 0; q < 4; ++q) {
    int f = tid + 256*q;
    int k = f >> 4, c4 = (f & 15) << 2;
    float4 tv = *(const float4*)&ACC3[(size_t)bh*4096 + f*4];
    float ri = 1.0f / S3[bh*64 + k];
    Ycol[(c4+0)*MATP + k] = tv.x * ri;
    Ycol[(c4+1)*MATP + k] = tv.y * ri;
    Ycol[(c4+2)*MATP + k] = tv.z * ri;
    Ycol[(c4+3)*MATP + k] = tv.w * ri;
  }
  __syncthreads();
  mm_mfma<false, false, false, true>(Vmrow, Ycol, 0.f, 1.0f, nullptr, nullptr, W + (size_t)bh*4096, wid, lane);
}

// ---------------- Kernel D: out = softmax(q k_lm^T) @ W ----------------
__global__ __launch_bounds__(256, 3) void out_kernel(
    const float* __restrict__ Q, const float* __restrict__ klm,
    const float* __restrict__ W, float* __restrict__ Out) {
  __shared__ alignas(16) short KlH[64*64], KlL[64*64];  // klm [l][d] planes
  __shared__ alignas(16) short WtH[64*64], WtL[64*64];  // W^T [d][l] planes
  __shared__ alignas(16) float Prow[64*MATP];           // P fp32 [n][l]
  const int bh = blockIdx.y, b = bh >> 4, h = bh & 15;
  const int n0 = blockIdx.x * 64;
  const int tid = threadIdx.x;
  const int wid = tid >> 6, lane = tid & 63;
  const int lr = lane & 15, lg = lane >> 4;
  const int m0 = wid*16 + lg*4;

  // stage klm planes (8 floats/thread/iter, b128 swizzled writes)
#pragma unroll
  for (int q2 = 0; q2 < 2; ++q2) {
    int f = tid + 256*q2;
    int r = f >> 3, c = f & 7;
    const float* kp = &klm[(size_t)bh*4096 + r*64 + c*8];
    float kf[8];
    *(float4*)&kf[0] = *(const float4*)kp;
    *(float4*)&kf[4] = *(const float4*)(kp + 4);
    bf16x8 khv, klv; split8(kf, khv, klv);
    int A = planeAddr(r, c);
    *(bf16x8*)((char*)KlH + A) = khv;
    *(bf16x8*)((char*)KlL + A) = klv;
  }
  // stage W^T planes via in-wave transpose
  const int dW = 4*lr + lg;
#pragma unroll
  for (int q = 0; q < 4; ++q) {
    int f = tid + 256*q;
    int r = f >> 4, c4 = (f & 15) << 2;
    float4 wv = *(const float4*)&W[(size_t)bh*4096 + r*64 + c4];
    float x[4] = {wv.x, wv.y, wv.z, wv.w};
    xpose4(x, lane);
    int nb = 16*q + 4*wid;
    s16x4 wh, wl; split4(x, wh, wl);
    int B = (dW << 7) + (nb << 1);
    B ^= (dW & 7) << 4;
    *(s16x4*)((char*)WtH + B) = wh;
    *(s16x4*)((char*)WtL + B) = wl;
  }

  // Q A-fragments -> registers (scaled, split once)
  bf16x8 qh[2], qlo[2];
#pragma unroll
  for (int ks = 0; ks < 2; ++ks) {
    const float* qp = Q + ((size_t)b*NN + n0 + wid*16 + lr)*CC + h*HD + ks*32 + lg*8;
    float qf[8];
    *(float4*)&qf[0] = *(const float4*)qp;
    *(float4*)&qf[4] = *(const float4*)(qp + 4);
#pragma unroll
    for (int i = 0; i < 8; ++i) qf[i] *= 0.125f;
    split8(qf, qh[ks], qlo[ks]);
  }
  __syncthreads();

  // GEMM1: z[n][l] = sum_d Q[n][d] * klm[l][d]
  f32x4 zacc[4];
#pragma unroll
  for (int t = 0; t < 4; ++t) zacc[t] = (f32x4){0.f, 0.f, 0.f, 0.f};
#pragma unroll
  for (int ks = 0; ks < 2; ++ks) {
#pragma unroll
    for (int tn = 0; tn < 4; ++tn) {
      bf16x8 bh_ = ldP(KlH, tn*16 + lr, 4*ks + lg);
      bf16x8 bl_ = ldP(KlL, tn*16 + lr, 4*ks + lg);
      zacc[tn] = __builtin_amdgcn_mfma_f32_16x16x32_bf16(qh[ks], bh_, zacc[tn], 0, 0, 0);
      zacc[tn] = __builtin_amdgcn_mfma_f32_16x16x32_bf16(qh[ks], bl_, zacc[tn], 0, 0, 0);
      zacc[tn] = __builtin_amdgcn_mfma_f32_16x16x32_bf16(qlo[ks], bh_, zacc[tn], 0, 0, 0);
    }
  }
  // softmax rows -> own rows of Prow
  float e[4][4];
#pragma unroll
  for (int tn = 0; tn < 4; ++tn)
#pragma unroll
    for (int r = 0; r < 4; ++r) e[tn][r] = __expf(zacc[tn][r]);
#pragma unroll
  for (int r = 0; r < 4; ++r) {
    float t = e[0][r] + e[1][r] + e[2][r] + e[3][r];
    t = shfl_sum16(t);
    float ri = 1.0f / t;
#pragma unroll
    for (int tn = 0; tn < 4; ++tn) e[tn][r] *= ri;
  }
#pragma unroll
  for (int tn = 0; tn < 4; ++tn) {
    const int n = tn*16 + lr;
#pragma unroll
    for (int r = 0; r < 4; ++r) Prow[(m0+r)*MATP + n] = e[tn][r];
  }

  // GEMM2: o[n][d] = sum_l P[n][l] * W[l][d]
  f32x4 oacc[4];
#pragma unroll
  for (int t = 0; t < 4; ++t) oacc[t] = (f32x4){0.f, 0.f, 0.f, 0.f};
#pragma unroll
  for (int ks = 0; ks < 2; ++ks) {
    float fa[8];
    const float* ap = Prow + (wid*16 + lr)*MATP + ks*32 + lg*8;
    *(float4*)&fa[0] = *(const float4*)ap;
    *(float4*)&fa[4] = *(const float4*)(ap + 4);
    bf16x8 ah, al; split8(fa, ah, al);
#pragma unroll
    for (int tn = 0; tn < 4; ++tn) {
      bf16x8 bh_ = ldP(WtH, tn*16 + lr, 4*ks + lg);
      bf16x8 bl_ = ldP(WtL, tn*16 + lr, 4*ks + lg);
      oacc[tn] = __builtin_amdgcn_mfma_f32_16x16x32_bf16(ah, bh_, oacc[tn], 0, 0, 0);
      oacc[tn] = __builtin_amdgcn_mfma_f32_16x16x32_bf16(ah, bl_, oacc[tn], 0, 0, 0);
      oacc[tn] = __builtin_amdgcn_mfma_f32_16x16x32_bf16(al, bh_, oacc[tn], 0, 0, 0);
    }
  }
#pragma unroll
  for (int tn = 0; tn < 4; ++tn) {
    const int d = tn*16 + lr;
#pragma unroll
    for (int r = 0; r < 4; ++r)
      Out[((size_t)b*NN + n0 + m0 + r)*CC + h*HD + d] = oacc[tn][r];
  }
}

// ---------------- host ----------------
extern "C" void kernel_launch(void* const* d_in, const int* in_sizes, int n_in,
                              void* d_out, int out_size, void* d_ws, size_t ws_size,
                              hipStream_t stream) {
  const float* Q = (const float*)d_in[0];
  const float* K = (const float*)d_in[1];
  const float* V = (const float*)d_in[2];
  float* out = (float*)d_out;
  float* ws  = (float*)d_ws;

  float* qlm  = ws;               // 262144
  float* klm  = ws + 262144;      // 262144
  float* S3   = ws + 524288;      // 4096
  float* ACC3 = ws + 528384;      // 262144
  float* Wm   = ws + 790528;      // 262144

  size_t shC = (size_t)(7*MATE + 4)*sizeof(float);   // ~122 KB
  hipFuncSetAttribute((const void*)inv_kernel,
                      hipFuncAttributeMaxDynamicSharedMemorySize, (int)shC);

  hipMemsetAsync(S3, 0, (4096 + 262144)*sizeof(float), stream);

  lm_kernel <<<dim3(16, BHN), 256, 0, stream>>>(Q, K, qlm, klm);
  k3v_kernel<<<dim3(32, BHN), 256, 0, stream>>>(K, V, qlm, S3, ACC3);
  inv_kernel<<<dim3(BHN),     256, shC, stream>>>(qlm, klm, S3, ACC3, Wm);
  out_kernel<<<dim3(64, BHN), 256, 0, stream>>>(Q, klm, Wm, out);
}

// Round 7
// 141.042 us; speedup vs baseline: 6.3275x; 1.0471x over previous
//
#include <hip/hip_runtime.h>
#include <math.h>

#define BB 4
#define NN 4096
#define CC 1024
#define HH 16
#define HD 64
#define LM 64
#define SEG 64
#define BHN (BB*HH)          // 64
#define MATP 68              // fp32 row stride (inv buffers + Erow/Prow): 272B rows, 16B-aligned
#define MATE (64*MATP)

typedef __attribute__((ext_vector_type(8))) short bf16x8;
typedef __attribute__((ext_vector_type(4))) short s16x4;
typedef __attribute__((ext_vector_type(4))) float f32x4;

__device__ __forceinline__ float shfl_sum16(float v) {
  v += __shfl_xor(v, 1, 16);
  v += __shfl_xor(v, 2, 16);
  v += __shfl_xor(v, 4, 16);
  v += __shfl_xor(v, 8, 16);
  return v;
}

// split fp32 -> bf16 hi (chop) + bf16 lo (chop of residual); rel err ~2^-16
__device__ __forceinline__ void split8(const float* f, bf16x8& hi, bf16x8& lo) {
#pragma unroll
  for (int i = 0; i < 8; ++i) {
    unsigned u = __builtin_bit_cast(unsigned, f[i]);
    float hf = __builtin_bit_cast(float, u & 0xFFFF0000u);
    hi[i] = (short)(u >> 16);
    float l = f[i] - hf;
    unsigned ul = __builtin_bit_cast(unsigned, l);
    lo[i] = (short)(ul >> 16);
  }
}

__device__ __forceinline__ void split4(const float* f, s16x4& hi, s16x4& lo) {
#pragma unroll
  for (int i = 0; i < 4; ++i) {
    unsigned u = __builtin_bit_cast(unsigned, f[i]);
    float hf = __builtin_bit_cast(float, u & 0xFFFF0000u);
    hi[i] = (short)(u >> 16);
    float l = f[i] - hf;
    unsigned ul = __builtin_bit_cast(unsigned, l);
    lo[i] = (short)(ul >> 16);
  }
}

// m214-style plane: 64 rows x 64 shorts (128B rows), byte ^= (row&7)<<4.
__device__ __forceinline__ int planeAddr(int row, int cd) {
  int B = (row << 7) + (cd << 4);
  return B ^ ((row & 7) << 4);
}
__device__ __forceinline__ bf16x8 ldP(const short* __restrict__ P, int row, int cd) {
  return *(const bf16x8*)((const char*)P + planeAddr(row, cd));
}

// in-wave 4x4 transpose among lanes {l, l^16, l^32, l^48}
__device__ __forceinline__ void xpose4(float x[4], int lane) {
  bool p1 = (lane >> 4) & 1;
  float s0 = p1 ? x[0] : x[1], s1 = p1 ? x[2] : x[3];
  float r0 = __shfl_xor(s0, 16, 64), r1 = __shfl_xor(s1, 16, 64);
  if (p1) { x[0] = r0; x[2] = r1; } else { x[1] = r0; x[3] = r1; }
  bool p2 = (lane >> 5) & 1;
  s0 = p2 ? x[0] : x[2]; s1 = p2 ? x[1] : x[3];
  r0 = __shfl_xor(s0, 32, 64); r1 = __shfl_xor(s1, 32, 64);
  if (p2) { x[0] = r0; x[1] = r1; } else { x[2] = r0; x[3] = r1; }
}

// ---------------- Kernel A: landmark means ----------------
__global__ __launch_bounds__(256) void lm_kernel(
    const float* __restrict__ Q, const float* __restrict__ K,
    float* __restrict__ qlm, float* __restrict__ klm) {
  int bh = blockIdx.y; int b = bh >> 4; int h = bh & 15;
  int tid = threadIdx.x;
  int l = blockIdx.x * 4 + (tid >> 6);
  int d = tid & 63;
  const float* qbase = Q + ((size_t)b*NN + (size_t)l*SEG)*CC + h*HD + d;
  const float* kbase = K + ((size_t)b*NN + (size_t)l*SEG)*CC + h*HD + d;
  float sq = 0.f, sk = 0.f;
#pragma unroll 8
  for (int s = 0; s < SEG; ++s) {
    sq += qbase[(size_t)s*CC];
    sk += kbase[(size_t)s*CC];
  }
  qlm[(size_t)bh*4096 + l*64 + d] = sq * (1.0f/(64.0f*8.0f));
  klm[(size_t)bh*4096 + l*64 + d] = sk * (1.0f/64.0f);
}

// ---------------- Kernel B: partials of kernel_3 @ V ----------------
__global__ __launch_bounds__(256, 3) void k3v_kernel(
    const float* __restrict__ K, const float* __restrict__ V,
    const float* __restrict__ qlm,
    float* __restrict__ S3, float* __restrict__ ACC3) {
  __shared__ alignas(16) short KEh[64*64], KEl[64*64];  // K tile [n][d] planes
  __shared__ alignas(16) short VtH[64*64], VtL[64*64];  // V^T [d][n] planes
  __shared__ alignas(16) float Erow[64*MATP];           // E fp32 [l][n]
  const int bh = blockIdx.y, b = bh >> 4, h = bh & 15;
  const int tile = blockIdx.x, tid = threadIdx.x;
  const int wid = tid >> 6, lane = tid & 63;
  const int lr = lane & 15, lg = lane >> 4;
  const int m0 = wid*16 + lg*4;

  bf16x8 qh[2], ql[2];
#pragma unroll
  for (int ks = 0; ks < 2; ++ks) {
    const float* qp = qlm + (size_t)bh*4096 + (wid*16 + lr)*64 + ks*32 + lg*8;
    float qf[8];
    *(float4*)&qf[0] = *(const float4*)qp;
    *(float4*)&qf[4] = *(const float4*)(qp + 4);
    split8(qf, qh[ks], ql[ks]);
  }

  f32x4 acc2[4];
#pragma unroll
  for (int t = 0; t < 4; ++t) acc2[t] = (f32x4){0.f, 0.f, 0.f, 0.f};
  float srow[4] = {0.f, 0.f, 0.f, 0.f};

  const int rk0 = tid >> 3,        ck = tid & 7;
  const int rk1 = (tid + 256) >> 3;
  const int dV  = 4*lr + lg;

  float4 gk[2][2], gv[4];

#define K3V_LOAD(SUB)                                                          \
  {                                                                            \
    const int n0_ = tile*128 + (SUB)*64;                                       \
    const float* kb0 = &K[((size_t)b*NN + n0_ + rk0)*CC + h*HD + ck*8];        \
    const float* kb1 = &K[((size_t)b*NN + n0_ + rk1)*CC + h*HD + ck*8];        \
    gk[0][0] = *(const float4*)kb0;  gk[0][1] = *(const float4*)(kb0 + 4);     \
    gk[1][0] = *(const float4*)kb1;  gk[1][1] = *(const float4*)(kb1 + 4);     \
    _Pragma("unroll")                                                          \
    for (int q = 0; q < 4; ++q) {                                              \
      int f = tid + 256*q;                                                     \
      int r = f >> 4, c4 = (f & 15) << 2;                                      \
      gv[q] = *(const float4*)&V[((size_t)b*NN + n0_ + r)*CC + h*HD + c4];     \
    }                                                                          \
  }

#define K3V_WRITE()                                                            \
  {                                                                            \
    _Pragma("unroll")                                                          \
    for (int q2 = 0; q2 < 2; ++q2) {                                           \
      float kf[8];                                                             \
      *(float4*)&kf[0] = gk[q2][0];                                            \
      *(float4*)&kf[4] = gk[q2][1];                                            \
      bf16x8 khv, klv; split8(kf, khv, klv);                                   \
      int r = q2 ? rk1 : rk0;                                                  \
      int A = planeAddr(r, ck);                                                \
      *(bf16x8*)((char*)KEh + A) = khv;                                        \
      *(bf16x8*)((char*)KEl + A) = klv;                                        \
    }                                                                          \
    _Pragma("unroll")                                                          \
    for (int q = 0; q < 4; ++q) {                                              \
      float x[4] = {gv[q].x, gv[q].y, gv[q].z, gv[q].w};                       \
      xpose4(x, lane);                                                         \
      int nb = 16*q + 4*wid;                                                   \
      s16x4 vh, vl; split4(x, vh, vl);                                         \
      int B = (dV << 7) + (nb << 1);                                           \
      B ^= (dV & 7) << 4;                                                      \
      *(s16x4*)((char*)VtH + B) = vh;                                          \
      *(s16x4*)((char*)VtL + B) = vl;                                          \
    }                                                                          \
  }

#define K3V_COMPUTE()                                                          \
  {                                                                            \
    f32x4 zacc[4];                                                             \
    _Pragma("unroll")                                                          \
    for (int t = 0; t < 4; ++t) zacc[t] = (f32x4){0.f, 0.f, 0.f, 0.f};        \
    _Pragma("unroll")                                                          \
    for (int ks = 0; ks < 2; ++ks) {                                           \
      _Pragma("unroll")                                                        \
      for (int tn = 0; tn < 4; ++tn) {                                         \
        bf16x8 bh_ = ldP(KEh, tn*16 + lr, 4*ks + lg);                          \
        bf16x8 bl_ = ldP(KEl, tn*16 + lr, 4*ks + lg);                          \
        zacc[tn] = __builtin_amdgcn_mfma_f32_16x16x32_bf16(qh[ks], bh_, zacc[tn], 0, 0, 0); \
        zacc[tn] = __builtin_amdgcn_mfma_f32_16x16x32_bf16(qh[ks], bl_, zacc[tn], 0, 0, 0); \
        zacc[tn] = __builtin_amdgcn_mfma_f32_16x16x32_bf16(ql[ks], bh_, zacc[tn], 0, 0, 0); \
      }                                                                        \
    }                                                                          \
    float e[4][4];                                                             \
    _Pragma("unroll")                                                          \
    for (int tn = 0; tn < 4; ++tn)                                             \
      _Pragma("unroll")                                                        \
      for (int r = 0; r < 4; ++r) e[tn][r] = __expf(zacc[tn][r]);              \
    _Pragma("unroll")                                                          \
    for (int r = 0; r < 4; ++r) {                                              \
      float t = e[0][r] + e[1][r] + e[2][r] + e[3][r];                         \
      srow[r] += shfl_sum16(t);                                                \
    }                                                                          \
    _Pragma("unroll")                                                          \
    for (int tn = 0; tn < 4; ++tn) {                                           \
      const int n = tn*16 + lr;                                                \
      _Pragma("unroll")                                                        \
      for (int r = 0; r < 4; ++r) Erow[(m0 + r)*MATP + n] = e[tn][r];          \
    }                                                                          \
    _Pragma("unroll")                                                          \
    for (int ks = 0; ks < 2; ++ks) {                                           \
      float fa[8];                                                             \
      const float* ap = Erow + (wid*16 + lr)*MATP + ks*32 + lg*8;              \
      *(float4*)&fa[0] = *(const float4*)ap;                                   \
      *(float4*)&fa[4] = *(const float4*)(ap + 4);                             \
      bf16x8 ah, al; split8(fa, ah, al);                                       \
      _Pragma("unroll")                                                        \
      for (int tn = 0; tn < 4; ++tn) {                                         \
        bf16x8 bh_ = ldP(VtH, tn*16 + lr, 4*ks + lg);                          \
        bf16x8 bl_ = ldP(VtL, tn*16 + lr, 4*ks + lg);                          \
        acc2[tn] = __builtin_amdgcn_mfma_f32_16x16x32_bf16(ah, bh_, acc2[tn], 0, 0, 0); \
        acc2[tn] = __builtin_amdgcn_mfma_f32_16x16x32_bf16(ah, bl_, acc2[tn], 0, 0, 0); \
        acc2[tn] = __builtin_amdgcn_mfma_f32_16x16x32_bf16(al, bh_, acc2[tn], 0, 0, 0); \
      }                                                                        \
    }                                                                          \
  }

  K3V_LOAD(0)
  K3V_WRITE()
  __syncthreads();
  K3V_LOAD(1)
  K3V_COMPUTE()
  __syncthreads();
  K3V_WRITE()
  __syncthreads();
  K3V_COMPUTE()

  if (lr == 0) {
#pragma unroll
    for (int r = 0; r < 4; ++r)
      atomicAdd(&S3[bh*64 + m0 + r], srow[r]);
  }
#pragma unroll
  for (int tn = 0; tn < 4; ++tn)
#pragma unroll
    for (int r = 0; r < 4; ++r)
      atomicAdd(&ACC3[(size_t)bh*4096 + (m0 + r)*64 + tn*16 + lr], acc2[tn][r]);
}

// ---------------- Kernel C: kernel_2 softmax + Newton-Schulz ----------------
// 1024 threads = 16 waves; wave wid -> tile (wr = wid&3, tn = wid>>2): 16x16 output.
template<bool FUSE, bool HR, bool HC, bool HG>
__device__ __forceinline__ void mm_mfma(
    const float* __restrict__ Arow, const float* __restrict__ Scol,
    float diagc, float scale,
    float* __restrict__ OutRow, float* __restrict__ OutCol, float* __restrict__ OutGlob,
    int wr, int tn, int lane) {
  const int lr = lane & 15, lg = lane >> 4;
  f32x4 acc = (f32x4){0.f, 0.f, 0.f, 0.f};

#pragma unroll
  for (int ks = 0; ks < 2; ++ks) {
    const int kb = ks*32 + lg*8;
    float fa[8];
    const float* ap = Arow + (wr*16 + lr)*MATP + kb;
    *(float4*)&fa[0] = *(const float4*)ap;
    *(float4*)&fa[4] = *(const float4*)(ap + 4);
    bf16x8 ah, al; split8(fa, ah, al);
    float fb[8];
    const float* bp = Scol + (tn*16 + lr)*MATP + kb;
    *(float4*)&fb[0] = *(const float4*)bp;
    *(float4*)&fb[4] = *(const float4*)(bp + 4);
    if (FUSE) {
      int diff = (tn*16 + lr) - kb;
#pragma unroll
      for (int i = 0; i < 8; ++i) fb[i] = (i == diff ? diagc : 0.f) - fb[i];
    }
    bf16x8 bh_, bl_; split8(fb, bh_, bl_);
    acc = __builtin_amdgcn_mfma_f32_16x16x32_bf16(ah, bh_, acc, 0, 0, 0);
    acc = __builtin_amdgcn_mfma_f32_16x16x32_bf16(ah, bl_, acc, 0, 0, 0);
    acc = __builtin_amdgcn_mfma_f32_16x16x32_bf16(al, bh_, acc, 0, 0, 0);
  }
  __syncthreads();   // all reads done before any overwrite
  const int n = tn*16 + lr, m0 = wr*16 + lg*4;
  float v0 = scale*acc[0], v1 = scale*acc[1], v2 = scale*acc[2], v3 = scale*acc[3];
  if (HC) *(float4*)&OutCol[n*MATP + m0] = make_float4(v0, v1, v2, v3);
  if (HR) {
    OutRow[(m0+0)*MATP + n] = v0;
    OutRow[(m0+1)*MATP + n] = v1;
    OutRow[(m0+2)*MATP + n] = v2;
    OutRow[(m0+3)*MATP + n] = v3;
  }
  if (HG) {
    OutGlob[(m0+0)*64 + n] = v0;
    OutGlob[(m0+1)*64 + n] = v1;
    OutGlob[(m0+2)*64 + n] = v2;
    OutGlob[(m0+3)*64 + n] = v3;
  }
  __syncthreads();   // writes visible to next mm
}

__global__ __launch_bounds__(1024, 1) void inv_kernel(
    const float* __restrict__ qlm, const float* __restrict__ klm,
    const float* __restrict__ S3, const float* __restrict__ ACC3,
    float* __restrict__ W) {
  extern __shared__ float sm[];
  float* K2row = sm;
  float* Vmrow = sm + 1*MATE;
  float* Vmcol = sm + 2*MATE;
  float* Xrow  = sm + 3*MATE;
  float* Xcol  = sm + 4*MATE;
  float* Ycol  = sm + 5*MATE;
  float* Zcol  = sm + 6*MATE;
  float* rs    = sm + 7*MATE;        // 64 rows x 4 tn partials
  float* rinv  = rs + 256;           // 64
  float* red   = rinv + 64;          // 1
  const int bh = blockIdx.x, tid = threadIdx.x;
  const int wid = tid >> 6, lane = tid & 63;
  const int wr = wid & 3, tn = wid >> 2;
  const int lr = lane & 15, lg = lane >> 4;
  const int m0 = wr*16 + lg*4, n = tn*16 + lr;

  // stage qlm -> Xrow, klm -> Xcol (1 float4 per thread)
  {
    int f = tid, r = f >> 4, c4 = (f & 15) << 2;
    *(float4*)&Xrow[r*MATP + c4] = *(const float4*)&qlm[(size_t)bh*4096 + f*4];
    *(float4*)&Xcol[r*MATP + c4] = *(const float4*)&klm[(size_t)bh*4096 + f*4];
  }
  __syncthreads();

  // z tile = qlm @ klm^T (one 16x16 per wave)
  {
    f32x4 zacc = (f32x4){0.f, 0.f, 0.f, 0.f};
#pragma unroll
    for (int ks = 0; ks < 2; ++ks) {
      const int kb = ks*32 + lg*8;
      float fa[8];
      const float* ap = Xrow + (wr*16 + lr)*MATP + kb;
      *(float4*)&fa[0] = *(const float4*)ap;
      *(float4*)&fa[4] = *(const float4*)(ap + 4);
      bf16x8 ah, al; split8(fa, ah, al);
      float fb[8];
      const float* bp = Xcol + (tn*16 + lr)*MATP + kb;
      *(float4*)&fb[0] = *(const float4*)bp;
      *(float4*)&fb[4] = *(const float4*)(bp + 4);
      bf16x8 bh_, bl_; split8(fb, bh_, bl_);
      zacc = __builtin_amdgcn_mfma_f32_16x16x32_bf16(ah, bh_, zacc, 0, 0, 0);
      zacc = __builtin_amdgcn_mfma_f32_16x16x32_bf16(ah, bl_, zacc, 0, 0, 0);
      zacc = __builtin_amdgcn_mfma_f32_16x16x32_bf16(al, bh_, zacc, 0, 0, 0);
    }
    float e[4];
#pragma unroll
    for (int r = 0; r < 4; ++r) e[r] = __expf(zacc[r]);
    // cross-wave row sums: in-wave 16-col partial, then LDS partials over tn
    float part[4];
#pragma unroll
    for (int r = 0; r < 4; ++r) part[r] = shfl_sum16(e[r]);
    if (lr == 0) {
#pragma unroll
      for (int r = 0; r < 4; ++r) rs[(m0 + r)*4 + tn] = part[r];
    }
    __syncthreads();
    if (tid < 64)
      rinv[tid] = 1.0f / (rs[tid*4] + rs[tid*4+1] + rs[tid*4+2] + rs[tid*4+3]);
    __syncthreads();
#pragma unroll
    for (int r = 0; r < 4; ++r)
      K2row[(m0+r)*MATP + n] = e[r] * rinv[m0 + r];
  }
  __syncthreads();

  // column sums -> denom = max_j ; red = 1/denom
  if (tid < 64) {
    float c = 0.f;
#pragma unroll 8
    for (int i = 0; i < 64; ++i) c += K2row[i*MATP + tid];
#pragma unroll
    for (int m = 1; m < 64; m <<= 1) c = fmaxf(c, __shfl_xor(c, m, 64));
    if (tid == 0) red[0] = 1.0f / c;
  }
  __syncthreads();
  const float invden = red[0];

  // Vm init: Vmcol = K2*invden (copy), Vmrow = K2^T*invden (scatter)
  {
    int f = tid, i = f >> 4, c4 = (f & 15) << 2;
    float4 kv = *(const float4*)&K2row[i*MATP + c4];
    kv.x *= invden; kv.y *= invden; kv.z *= invden; kv.w *= invden;
    *(float4*)&Vmcol[i*MATP + c4] = kv;
    Vmrow[(c4+0)*MATP + i] = kv.x;
    Vmrow[(c4+1)*MATP + i] = kv.y;
    Vmrow[(c4+2)*MATP + i] = kv.z;
    Vmrow[(c4+3)*MATP + i] = kv.w;
  }
  __syncthreads();

  for (int it = 0; it < 6; ++it) {
    mm_mfma<false, true,  true,  false>(K2row, Vmcol, 0.f,  1.0f,  Xrow, Xcol, nullptr, wr, tn, lane);
    mm_mfma<true,  false, true,  false>(Xrow,  Xcol,  7.f,  1.0f,  nullptr, Ycol, nullptr, wr, tn, lane);
    mm_mfma<true,  false, true,  false>(Xrow,  Ycol,  15.f, 1.0f,  nullptr, Zcol, nullptr, wr, tn, lane);
    mm_mfma<true,  true,  true,  false>(Vmrow, Zcol,  13.f, 0.25f, Vmrow, Vmcol, nullptr, wr, tn, lane);
  }

  // T = ACC3/S3 staged transposed into Ycol, then W = Vm @ T -> global
  {
    int f = tid, k = f >> 4, c4 = (f & 15) << 2;
    float4 tv = *(const float4*)&ACC3[(size_t)bh*4096 + f*4];
    float ri = 1.0f / S3[bh*64 + k];
    Ycol[(c4+0)*MATP + k] = tv.x * ri;
    Ycol[(c4+1)*MATP + k] = tv.y * ri;
    Ycol[(c4+2)*MATP + k] = tv.z * ri;
    Ycol[(c4+3)*MATP + k] = tv.w * ri;
  }
  __syncthreads();
  mm_mfma<false, false, false, true>(Vmrow, Ycol, 0.f, 1.0f, nullptr, nullptr, W + (size_t)bh*4096, wr, tn, lane);
}

// ---------------- Kernel D: out = softmax(q k_lm^T) @ W ----------------
__global__ __launch_bounds__(256, 3) void out_kernel(
    const float* __restrict__ Q, const float* __restrict__ klm,
    const float* __restrict__ W, float* __restrict__ Out) {
  __shared__ alignas(16) short KlH[64*64], KlL[64*64];
  __shared__ alignas(16) short WtH[64*64], WtL[64*64];
  __shared__ alignas(16) float Prow[64*MATP];
  const int bh = blockIdx.y, b = bh >> 4, h = bh & 15;
  const int n0 = blockIdx.x * 64;
  const int tid = threadIdx.x;
  const int wid = tid >> 6, lane = tid & 63;
  const int lr = lane & 15, lg = lane >> 4;
  const int m0 = wid*16 + lg*4;

#pragma unroll
  for (int q2 = 0; q2 < 2; ++q2) {
    int f = tid + 256*q2;
    int r = f >> 3, c = f & 7;
    const float* kp = &klm[(size_t)bh*4096 + r*64 + c*8];
    float kf[8];
    *(float4*)&kf[0] = *(const float4*)kp;
    *(float4*)&kf[4] = *(const float4*)(kp + 4);
    bf16x8 khv, klv; split8(kf, khv, klv);
    int A = planeAddr(r, c);
    *(bf16x8*)((char*)KlH + A) = khv;
    *(bf16x8*)((char*)KlL + A) = klv;
  }
  const int dW = 4*lr + lg;
#pragma unroll
  for (int q = 0; q < 4; ++q) {
    int f = tid + 256*q;
    int r = f >> 4, c4 = (f & 15) << 2;
    float4 wv = *(const float4*)&W[(size_t)bh*4096 + r*64 + c4];
    float x[4] = {wv.x, wv.y, wv.z, wv.w};
    xpose4(x, lane);
    int nb = 16*q + 4*wid;
    s16x4 wh, wl; split4(x, wh, wl);
    int B = (dW << 7) + (nb << 1);
    B ^= (dW & 7) << 4;
    *(s16x4*)((char*)WtH + B) = wh;
    *(s16x4*)((char*)WtL + B) = wl;
  }

  bf16x8 qh[2], qlo[2];
#pragma unroll
  for (int ks = 0; ks < 2; ++ks) {
    const float* qp = Q + ((size_t)b*NN + n0 + wid*16 + lr)*CC + h*HD + ks*32 + lg*8;
    float qf[8];
    *(float4*)&qf[0] = *(const float4*)qp;
    *(float4*)&qf[4] = *(const float4*)(qp + 4);
#pragma unroll
    for (int i = 0; i < 8; ++i) qf[i] *= 0.125f;
    split8(qf, qh[ks], qlo[ks]);
  }
  __syncthreads();

  f32x4 zacc[4];
#pragma unroll
  for (int t = 0; t < 4; ++t) zacc[t] = (f32x4){0.f, 0.f, 0.f, 0.f};
#pragma unroll
  for (int ks = 0; ks < 2; ++ks) {
#pragma unroll
    for (int tn = 0; tn < 4; ++tn) {
      bf16x8 bh_ = ldP(KlH, tn*16 + lr, 4*ks + lg);
      bf16x8 bl_ = ldP(KlL, tn*16 + lr, 4*ks + lg);
      zacc[tn] = __builtin_amdgcn_mfma_f32_16x16x32_bf16(qh[ks], bh_, zacc[tn], 0, 0, 0);
      zacc[tn] = __builtin_amdgcn_mfma_f32_16x16x32_bf16(qh[ks], bl_, zacc[tn], 0, 0, 0);
      zacc[tn] = __builtin_amdgcn_mfma_f32_16x16x32_bf16(qlo[ks], bh_, zacc[tn], 0, 0, 0);
    }
  }
  float e[4][4];
#pragma unroll
  for (int tn = 0; tn < 4; ++tn)
#pragma unroll
    for (int r = 0; r < 4; ++r) e[tn][r] = __expf(zacc[tn][r]);
#pragma unroll
  for (int r = 0; r < 4; ++r) {
    float t = e[0][r] + e[1][r] + e[2][r] + e[3][r];
    t = shfl_sum16(t);
    float ri = 1.0f / t;
#pragma unroll
    for (int tn = 0; tn < 4; ++tn) e[tn][r] *= ri;
  }
#pragma unroll
  for (int tn = 0; tn < 4; ++tn) {
    const int n = tn*16 + lr;
#pragma unroll
    for (int r = 0; r < 4; ++r) Prow[(m0+r)*MATP + n] = e[tn][r];
  }

  f32x4 oacc[4];
#pragma unroll
  for (int t = 0; t < 4; ++t) oacc[t] = (f32x4){0.f, 0.f, 0.f, 0.f};
#pragma unroll
  for (int ks = 0; ks < 2; ++ks) {
    float fa[8];
    const float* ap = Prow + (wid*16 + lr)*MATP + ks*32 + lg*8;
    *(float4*)&fa[0] = *(const float4*)ap;
    *(float4*)&fa[4] = *(const float4*)(ap + 4);
    bf16x8 ah, al; split8(fa, ah, al);
#pragma unroll
    for (int tn = 0; tn < 4; ++tn) {
      bf16x8 bh_ = ldP(WtH, tn*16 + lr, 4*ks + lg);
      bf16x8 bl_ = ldP(WtL, tn*16 + lr, 4*ks + lg);
      oacc[tn] = __builtin_amdgcn_mfma_f32_16x16x32_bf16(ah, bh_, oacc[tn], 0, 0, 0);
      oacc[tn] = __builtin_amdgcn_mfma_f32_16x16x32_bf16(ah, bl_, oacc[tn], 0, 0, 0);
      oacc[tn] = __builtin_amdgcn_mfma_f32_16x16x32_bf16(al, bh_, oacc[tn], 0, 0, 0);
    }
  }
#pragma unroll
  for (int tn = 0; tn < 4; ++tn) {
    const int d = tn*16 + lr;
#pragma unroll
    for (int r = 0; r < 4; ++r)
      Out[((size_t)b*NN + n0 + m0 + r)*CC + h*HD + d] = oacc[tn][r];
  }
}

// ---------------- host ----------------
extern "C" void kernel_launch(void* const* d_in, const int* in_sizes, int n_in,
                              void* d_out, int out_size, void* d_ws, size_t ws_size,
                              hipStream_t stream) {
  const float* Q = (const float*)d_in[0];
  const float* K = (const float*)d_in[1];
  const float* V = (const float*)d_in[2];
  float* out = (float*)d_out;
  float* ws  = (float*)d_ws;

  float* qlm  = ws;               // 262144
  float* klm  = ws + 262144;      // 262144
  float* S3   = ws + 524288;      // 4096
  float* ACC3 = ws + 528384;      // 262144
  float* Wm   = ws + 790528;      // 262144

  size_t shC = (size_t)(7*MATE + 384)*sizeof(float);   // ~123 KB
  hipFuncSetAttribute((const void*)inv_kernel,
                      hipFuncAttributeMaxDynamicSharedMemorySize, (int)shC);

  hipMemsetAsync(S3, 0, (4096 + 262144)*sizeof(float), stream);

  lm_kernel <<<dim3(16, BHN), 256, 0, stream>>>(Q, K, qlm, klm);
  k3v_kernel<<<dim3(32, BHN), 256, 0, stream>>>(K, V, qlm, S3, ACC3);
  inv_kernel<<<dim3(BHN),    1024, shC, stream>>>(qlm, klm, S3, ACC3, Wm);
  out_kernel<<<dim3(64, BHN), 256, 0, stream>>>(Q, klm, Wm, out);
}